// Round 1
// baseline (877.382 us; speedup 1.0000x reference)
//
#include <hip/hip_runtime.h>
#include <cstdint>
#include <cstddef>

// Problem constants (from reference): N=100000, F_IN=64, F1=128, F2=64,
// E=3200000, NUM_GRAPHS=1024. N and E derived from in_sizes at launch.
#define NGRAPH 1024

// ---------------- graph preprocessing ----------------

__global__ void deg_count_kernel(const int* __restrict__ dst, int E, int* __restrict__ deg) {
    int i = blockIdx.x * blockDim.x + threadIdx.x;
    if (i < E) atomicAdd(&deg[dst[i]], 1);
}

__global__ void batch_count_kernel(const int* __restrict__ batch, int N, int* __restrict__ gcnt) {
    int i = blockIdx.x * blockDim.x + threadIdx.x;
    if (i < N) atomicAdd(&gcnt[batch[i]], 1);
}

// Block-local exclusive scan (1024/block) of deg -> row_off, block totals -> partials
__global__ void scan1_kernel(const int* __restrict__ deg, int* __restrict__ row_off,
                             int* __restrict__ partials, int N) {
    __shared__ int sh[1024];
    int tid = threadIdx.x;
    int idx = blockIdx.x * 1024 + tid;
    int v = (idx < N) ? deg[idx] : 0;
    sh[tid] = v; __syncthreads();
    for (int o = 1; o < 1024; o <<= 1) {
        int t = (tid >= o) ? sh[tid - o] : 0;
        __syncthreads();
        sh[tid] += t;
        __syncthreads();
    }
    if (idx < N) row_off[idx] = sh[tid] - v;      // exclusive (block-local)
    if (tid == 1023) partials[blockIdx.x] = sh[1023];
}

// Single-block exclusive scan of block partials (nb <= 128), in place
__global__ void scan2_kernel(int* __restrict__ partials, int nb) {
    __shared__ int sh[128];
    int tid = threadIdx.x;
    int v = (tid < nb) ? partials[tid] : 0;
    sh[tid] = v; __syncthreads();
    for (int o = 1; o < 128; o <<= 1) {
        int t = (tid >= o) ? sh[tid - o] : 0;
        __syncthreads();
        sh[tid] += t;
        __syncthreads();
    }
    if (tid < nb) partials[tid] = sh[tid] - v;
}

// Add block offsets; init cur (scatter cursors); set row_off[N] = E
__global__ void scan3_kernel(int* __restrict__ row_off, const int* __restrict__ partials,
                             int* __restrict__ cur, int N, int E) {
    int i = blockIdx.x * blockDim.x + threadIdx.x;
    if (i < N) {
        int v = row_off[i] + partials[i >> 10];
        row_off[i] = v;
        cur[i] = v;
    }
    if (i == 0) row_off[N] = E;
}

__global__ void dinv_kernel(const int* __restrict__ deg, float* __restrict__ dinv, int N) {
    int i = blockIdx.x * blockDim.x + threadIdx.x;
    if (i < N) dinv[i] = rsqrtf((float)(deg[i] + 1));   // +1 self loop
}

// Counting-sort edges by dst (order within a row irrelevant for a sum)
__global__ void scatter_kernel(const int* __restrict__ src, const int* __restrict__ dst,
                               int E, int* __restrict__ cur, int* __restrict__ esrc) {
    int i = blockIdx.x * blockDim.x + threadIdx.x;
    if (i < E) {
        int p = atomicAdd(&cur[dst[i]], 1);
        esrc[p] = src[i];
    }
}

// Exclusive scan of 1024 graph counts in one block; goff[1024] = N
__global__ void gscan_kernel(const int* __restrict__ gcnt, int* __restrict__ goff) {
    __shared__ int sh[1024];
    int tid = threadIdx.x;
    int v = gcnt[tid];
    sh[tid] = v; __syncthreads();
    for (int o = 1; o < 1024; o <<= 1) {
        int t = (tid >= o) ? sh[tid - o] : 0;
        __syncthreads();
        sh[tid] += t;
        __syncthreads();
    }
    goff[tid] = sh[tid] - v;
    if (tid == 1023) goff[1024] = sh[1023];
}

// xs[n][f] = x[n][f] * dinv[n]   (vectorized, 16 float4 per 64-wide row)
__global__ void scale_kernel(const float* __restrict__ x, const float* __restrict__ dinv,
                             float* __restrict__ xs, int n4) {
    int i = blockIdx.x * blockDim.x + threadIdx.x;
    if (i < n4) {
        float d = dinv[i >> 4];
        float4 v = ((const float4*)x)[i];
        v.x *= d; v.y *= d; v.z *= d; v.w *= d;
        ((float4*)xs)[i] = v;
    }
}

// ---------------- aggregation: out[n] = dinv[n]*(xs[n] + sum_{e in row(n)} xs[src_e]) (+bias)
// one 64-lane wave per node; lane = feature; 4x unrolled independent gathers
__global__ __launch_bounds__(256) void agg_kernel(const float* __restrict__ xs,
        const int* __restrict__ esrc, const int* __restrict__ row_off,
        const float* __restrict__ dinv, const float* __restrict__ bias,
        float* __restrict__ out, int N) {
    int n = blockIdx.x * 4 + (threadIdx.x >> 6);
    int lane = threadIdx.x & 63;
    if (n >= N) return;
    int beg = row_off[n], end = row_off[n + 1];
    float acc = xs[(size_t)n * 64 + lane];   // self loop term (already dinv-scaled)
    float a0 = 0.f, a1 = 0.f, a2 = 0.f, a3 = 0.f;
    int e = beg;
    for (; e + 4 <= end; e += 4) {
        int s0 = esrc[e], s1 = esrc[e + 1], s2 = esrc[e + 2], s3 = esrc[e + 3];
        a0 += xs[(size_t)s0 * 64 + lane];
        a1 += xs[(size_t)s1 * 64 + lane];
        a2 += xs[(size_t)s2 * 64 + lane];
        a3 += xs[(size_t)s3 * 64 + lane];
    }
    for (; e < end; ++e) acc += xs[(size_t)esrc[e] * 64 + lane];
    acc += (a0 + a1) + (a2 + a3);
    float v = dinv[n] * acc;
    if (bias) v += bias[lane];
    out[(size_t)n * 64 + lane] = v;
}

// ---------------- GEMM1: H[N,128] = relu(A[N,64] @ W[64,128] + b1)
// 64-node tile, full K=64 staged; 256 thr; per-thread 4 nodes x 8 feats
__global__ __launch_bounds__(256) void gemm1_kernel(const float* __restrict__ A,
        const float* __restrict__ W, const float* __restrict__ bias,
        float* __restrict__ H, int N) {
    __shared__ float As[64 * 68];    // pad 64->68 (16B-aligned rows, conflict-light)
    __shared__ float Ws[64 * 128];
    int tid = threadIdx.x;
    int m0 = blockIdx.x * 64;
    #pragma unroll
    for (int t = 0; t < 8; ++t) {            // W1: 8192 floats = 2048 float4
        int j = tid + t * 256;
        float4 v = ((const float4*)W)[j];    // k = j>>5, f4 = j&31
        *((float4*)&Ws[(j >> 5) * 128 + (j & 31) * 4]) = v;
    }
    #pragma unroll
    for (int t = 0; t < 4; ++t) {            // A tile: 4096 floats = 1024 float4
        int j = tid + t * 256;
        int node = j >> 4, c = j & 15;
        int gn = m0 + node;
        float4 v = make_float4(0.f, 0.f, 0.f, 0.f);
        if (gn < N) v = ((const float4*)A)[(size_t)gn * 16 + c];
        *((float4*)&As[node * 68 + c * 4]) = v;
    }
    __syncthreads();
    int tx = tid & 15, ty = tid >> 4;        // f0 = tx*8, nodes ty*4..+4
    float acc[4][8] = {};
    for (int k = 0; k < 64; ++k) {
        float a[4];
        #pragma unroll
        for (int i = 0; i < 4; ++i) a[i] = As[(ty * 4 + i) * 68 + k];
        float4 b0 = *((const float4*)&Ws[k * 128 + tx * 8]);
        float4 b1 = *((const float4*)&Ws[k * 128 + tx * 8 + 4]);
        #pragma unroll
        for (int i = 0; i < 4; ++i) {
            acc[i][0] = fmaf(a[i], b0.x, acc[i][0]);
            acc[i][1] = fmaf(a[i], b0.y, acc[i][1]);
            acc[i][2] = fmaf(a[i], b0.z, acc[i][2]);
            acc[i][3] = fmaf(a[i], b0.w, acc[i][3]);
            acc[i][4] = fmaf(a[i], b1.x, acc[i][4]);
            acc[i][5] = fmaf(a[i], b1.y, acc[i][5]);
            acc[i][6] = fmaf(a[i], b1.z, acc[i][6]);
            acc[i][7] = fmaf(a[i], b1.w, acc[i][7]);
        }
    }
    float4 bb0 = ((const float4*)bias)[tx * 2];
    float4 bb1 = ((const float4*)bias)[tx * 2 + 1];
    #pragma unroll
    for (int i = 0; i < 4; ++i) {
        int n = m0 + ty * 4 + i;
        if (n < N) {
            float4 o0, o1;
            o0.x = fmaxf(acc[i][0] + bb0.x, 0.f);
            o0.y = fmaxf(acc[i][1] + bb0.y, 0.f);
            o0.z = fmaxf(acc[i][2] + bb0.z, 0.f);
            o0.w = fmaxf(acc[i][3] + bb0.w, 0.f);
            o1.x = fmaxf(acc[i][4] + bb1.x, 0.f);
            o1.y = fmaxf(acc[i][5] + bb1.y, 0.f);
            o1.z = fmaxf(acc[i][6] + bb1.z, 0.f);
            o1.w = fmaxf(acc[i][7] + bb1.w, 0.f);
            *((float4*)&H[(size_t)n * 128 + tx * 8]) = o0;
            *((float4*)&H[(size_t)n * 128 + tx * 8 + 4]) = o1;
        }
    }
}

// ---------------- GEMM2: T[N,64] = (H[N,128] @ W2[128,64]) * dinv[n]
__global__ __launch_bounds__(256) void gemm2_kernel(const float* __restrict__ H,
        const float* __restrict__ W, const float* __restrict__ dinv,
        float* __restrict__ T, int N) {
    __shared__ float Hs[64 * 132];   // pad 128->132
    __shared__ float Ws[128 * 64];
    int tid = threadIdx.x;
    int m0 = blockIdx.x * 64;
    #pragma unroll
    for (int t = 0; t < 8; ++t) {            // W2: 8192 floats = 2048 float4
        int j = tid + t * 256;
        float4 v = ((const float4*)W)[j];    // k = j>>4, f4 = j&15
        *((float4*)&Ws[(j >> 4) * 64 + (j & 15) * 4]) = v;
    }
    #pragma unroll
    for (int t = 0; t < 8; ++t) {            // H tile: 8192 floats
        int j = tid + t * 256;
        int node = j >> 5, c = j & 31;
        int gn = m0 + node;
        float4 v = make_float4(0.f, 0.f, 0.f, 0.f);
        if (gn < N) v = ((const float4*)H)[(size_t)gn * 32 + c];
        *((float4*)&Hs[node * 132 + c * 4]) = v;
    }
    __syncthreads();
    int tx = tid & 15, ty = tid >> 4;        // f0 = tx*4, nodes ty*4..+4
    float acc[4][4] = {};
    for (int k = 0; k < 128; ++k) {
        float a[4];
        #pragma unroll
        for (int i = 0; i < 4; ++i) a[i] = Hs[(ty * 4 + i) * 132 + k];
        float4 b = *((const float4*)&Ws[k * 64 + tx * 4]);
        #pragma unroll
        for (int i = 0; i < 4; ++i) {
            acc[i][0] = fmaf(a[i], b.x, acc[i][0]);
            acc[i][1] = fmaf(a[i], b.y, acc[i][1]);
            acc[i][2] = fmaf(a[i], b.z, acc[i][2]);
            acc[i][3] = fmaf(a[i], b.w, acc[i][3]);
        }
    }
    #pragma unroll
    for (int i = 0; i < 4; ++i) {
        int n = m0 + ty * 4 + i;
        if (n < N) {
            float d = dinv[n];
            float4 o;
            o.x = acc[i][0] * d; o.y = acc[i][1] * d;
            o.z = acc[i][2] * d; o.w = acc[i][3] * d;
            *((float4*)&T[(size_t)n * 64 + tx * 4]) = o;
        }
    }
}

// ---------------- readout: r[g] = [mean(h2 rows), max(h2 rows)]  (batch sorted)
__global__ __launch_bounds__(256) void readout_kernel(const float* __restrict__ h2,
        const int* __restrict__ goff, float* __restrict__ r) {
    int g = blockIdx.x;
    int beg = goff[g], end = goff[g + 1];
    int f = threadIdx.x & 63;
    int c = threadIdx.x >> 6;    // 0..3
    float s = 0.f, m = -3.4e38f;
    for (int n = beg + c; n < end; n += 4) {
        float v = h2[(size_t)n * 64 + f];
        s += v;
        m = fmaxf(m, v);
    }
    __shared__ float ss[4][64], sm[4][64];
    ss[c][f] = s; sm[c][f] = m;
    __syncthreads();
    if (c == 0) {
        float S = ss[0][f] + ss[1][f] + ss[2][f] + ss[3][f];
        float M = fmaxf(fmaxf(sm[0][f], sm[1][f]), fmaxf(sm[2][f], sm[3][f]));
        int cnt = end - beg;
        float mean = (cnt > 0) ? S / (float)cnt : 0.f;
        if (cnt == 0) M = 0.f;   // unreachable for this input distribution
        r[(size_t)g * 128 + f] = mean;
        r[(size_t)g * 128 + 64 + f] = M;
    }
}

// ---------------- head: out[g] = r[g] @ Wm + bm   (1024 x 128 @ 128 x 64)
__global__ __launch_bounds__(64) void head_kernel(const float* __restrict__ r,
        const float* __restrict__ Wm, const float* __restrict__ bm,
        float* __restrict__ out) {
    int g = blockIdx.x;
    int j = threadIdx.x;   // 0..63
    float acc = bm[j];
    #pragma unroll 4
    for (int k = 0; k < 128; ++k)
        acc = fmaf(r[(size_t)g * 128 + k], Wm[k * 64 + j], acc);
    out[(size_t)g * 64 + j] = acc;
}

extern "C" void kernel_launch(void* const* d_in, const int* in_sizes, int n_in,
                              void* d_out, int out_size, void* d_ws, size_t ws_size,
                              hipStream_t stream) {
    const float* x   = (const float*)d_in[0];
    const int*  adj  = (const int*)d_in[1];
    const int*  batch= (const int*)d_in[2];
    const float* W1  = (const float*)d_in[3];
    const float* b1  = (const float*)d_in[4];
    const float* W2  = (const float*)d_in[5];
    const float* b2  = (const float*)d_in[6];
    const float* Wm  = (const float*)d_in[7];
    const float* bm  = (const float*)d_in[8];
    float* out = (float*)d_out;

    const int N = in_sizes[0] / 64;
    const int E = in_sizes[1] / 2;
    const int* src = adj;
    const int* dst = adj + E;

    // ---- workspace carve (256B aligned) ----
    char* w = (char*)d_ws;
    size_t off = 0;
    auto carve = [&](size_t bytes) -> void* {
        void* p = w + off;
        off += (bytes + 255) & ~(size_t)255;
        return p;
    };
    int*   deg      = (int*)  carve((size_t)N * 4);
    float* dinv     = (float*)carve((size_t)N * 4);
    int*   row_off  = (int*)  carve((size_t)(N + 1) * 4);
    int*   cur      = (int*)  carve((size_t)N * 4);
    int*   partials = (int*)  carve(128 * 4);
    int*   esrc     = (int*)  carve((size_t)E * 4);
    int*   gcnt     = (int*)  carve(NGRAPH * 4);
    int*   goff     = (int*)  carve((NGRAPH + 1) * 4);
    float* xs       = (float*)carve((size_t)N * 64 * 4);   // reused as ts
    float* agg1     = (float*)carve((size_t)N * 64 * 4);   // reused as h2
    float* h1       = (float*)carve((size_t)N * 128 * 4);
    float* r        = (float*)carve((size_t)NGRAPH * 128 * 4);
    float* ts = xs;      // xs dead after agg1
    float* h2 = agg1;    // agg1 dead after gemm1

    const int nb = (N + 1023) / 1024;

    hipMemsetAsync(deg, 0, (size_t)N * 4, stream);
    hipMemsetAsync(gcnt, 0, NGRAPH * 4, stream);

    // CSR build + norms
    deg_count_kernel<<<(E + 255) / 256, 256, 0, stream>>>(dst, E, deg);
    batch_count_kernel<<<(N + 255) / 256, 256, 0, stream>>>(batch, N, gcnt);
    scan1_kernel<<<nb, 1024, 0, stream>>>(deg, row_off, partials, N);
    scan2_kernel<<<1, 128, 0, stream>>>(partials, nb);
    scan3_kernel<<<(N + 255) / 256, 256, 0, stream>>>(row_off, partials, cur, N, E);
    dinv_kernel<<<(N + 255) / 256, 256, 0, stream>>>(deg, dinv, N);
    scatter_kernel<<<(E + 255) / 256, 256, 0, stream>>>(src, dst, E, cur, esrc);
    gscan_kernel<<<1, 1024, 0, stream>>>(gcnt, goff);

    // conv1: xs = x*dinv ; agg1 = dinv*(S+I)xs ; h1 = relu(agg1@W1 + b1)
    scale_kernel<<<(N * 16 + 255) / 256, 256, 0, stream>>>(x, dinv, xs, N * 16);
    agg_kernel<<<(N + 3) / 4, 256, 0, stream>>>(xs, esrc, row_off, dinv, nullptr, agg1, N);
    gemm1_kernel<<<(N + 63) / 64, 256, 0, stream>>>(agg1, W1, b1, h1, N);

    // conv2: ts = (h1@W2)*dinv ; h2 = dinv*(S+I)ts + b2
    gemm2_kernel<<<(N + 63) / 64, 256, 0, stream>>>(h1, W2, dinv, ts, N);
    agg_kernel<<<(N + 3) / 4, 256, 0, stream>>>(ts, esrc, row_off, dinv, b2, h2, N);

    // readout + head
    readout_kernel<<<NGRAPH, 256, 0, stream>>>(h2, goff, r);
    head_kernel<<<NGRAPH, 64, 0, stream>>>(r, Wm, bm, out);
}

// Round 2
// 549.469 us; speedup vs baseline: 1.5968x; 1.5968x over previous
//
#include <hip/hip_runtime.h>
#include <cstdint>
#include <cstddef>

// Problem constants (from reference): N=100000, F_IN=64, F1=128, F2=64,
// E=3200000, NUM_GRAPHS=1024. N and E derived from in_sizes at launch.
#define NGRAPH 1024
#define CHUNK 16384      // edges per block in coarse pass (nblocks = ceil(E/CHUNK) <= 256)
#define MAXB 512         // max buckets (supports N <= 131072; here B=391)

// ================= two-level bucket CSR build =================
// bucket b = dst >> 8 (256 node ids per bucket). Edge word packs
// (dst & 255) << 24 | src   (needs src < 2^24; N=100000 ok).

// Pass A: per-block LDS histogram of buckets -> cnt[b*nblocks+blk], btot[b]
__global__ __launch_bounds__(256) void coarse_hist_kernel(const int* __restrict__ dst,
        int E, int nblocks, int B, int* __restrict__ cnt, int* __restrict__ btot) {
    __shared__ int h[MAXB];
    int blk = blockIdx.x, tid = threadIdx.x;
    for (int i = tid; i < B; i += 256) h[i] = 0;
    __syncthreads();
    int base = blk * CHUNK;
    #pragma unroll 4
    for (int it = 0; it < CHUNK / 256; ++it) {
        int i = base + tid + it * 256;
        if (i < E) atomicAdd(&h[dst[i] >> 8], 1);
    }
    __syncthreads();
    for (int b = tid; b < B; b += 256) {
        int c = h[b];
        cnt[b * nblocks + blk] = c;
        if (c) atomicAdd(&btot[b], c);
    }
}

// Exclusive scan of bucket totals -> bbase[0..B], bbase[B]=E (single block)
__global__ void bucket_scan_kernel(const int* __restrict__ btot, int* __restrict__ bbase,
                                   int B, int E) {
    __shared__ int sh[MAXB];
    int tid = threadIdx.x;
    int v = (tid < B) ? btot[tid] : 0;
    sh[tid] = v; __syncthreads();
    for (int o = 1; o < MAXB; o <<= 1) {
        int t = (tid >= o) ? sh[tid - o] : 0;
        __syncthreads();
        sh[tid] += t;
        __syncthreads();
    }
    if (tid < B) bbase[tid] = sh[tid] - v;
    if (tid == 0) bbase[B] = E;
}

// Per-bucket scan across blocks: cnt[b][blk] -> bbase[b] + excl prefix (in place)
__global__ __launch_bounds__(256) void offset_scan_kernel(int* __restrict__ cnt,
        const int* __restrict__ bbase, int nblocks) {
    __shared__ int sh[256];
    int b = blockIdx.x, tid = threadIdx.x;
    int v = (tid < nblocks) ? cnt[b * nblocks + tid] : 0;
    sh[tid] = v; __syncthreads();
    for (int o = 1; o < 256; o <<= 1) {
        int t = (tid >= o) ? sh[tid - o] : 0;
        __syncthreads();
        sh[tid] += t;
        __syncthreads();
    }
    if (tid < nblocks) cnt[b * nblocks + tid] = sh[tid] - v + bbase[b];
}

// Pass C: scatter packed edge words into bucket-grouped ebuck (coalesced-ish runs)
__global__ __launch_bounds__(256) void coarse_scatter_kernel(const int* __restrict__ src,
        const int* __restrict__ dst, int E, int nblocks, int B,
        const int* __restrict__ cnt, unsigned* __restrict__ ebuck) {
    __shared__ int loff[MAXB];
    int blk = blockIdx.x, tid = threadIdx.x;
    for (int b = tid; b < B; b += 256) loff[b] = cnt[b * nblocks + blk];
    __syncthreads();
    int base = blk * CHUNK;
    #pragma unroll 4
    for (int it = 0; it < CHUNK / 256; ++it) {
        int i = base + tid + it * 256;
        if (i < E) {
            int d = dst[i], s = src[i];
            int p = atomicAdd(&loff[d >> 8], 1);
            ebuck[p] = ((unsigned)(d & 255) << 24) | (unsigned)s;
        }
    }
}

// Pass D: one block per bucket. LDS histogram -> deg/dinv/row_off (bucket-major,
// globally monotone), then LDS-cursor scatter of src into esrc (L2-local window).
__global__ __launch_bounds__(256) void fine_kernel(const unsigned* __restrict__ ebuck,
        const int* __restrict__ bbase, int N, int E, int B,
        int* __restrict__ row_off, float* __restrict__ dinv, int* __restrict__ esrc) {
    __shared__ int hcnt[256];
    __shared__ int sc[256];
    __shared__ int loff[256];
    int b = blockIdx.x, tid = threadIdx.x;
    int beg = bbase[b], end = bbase[b + 1];
    hcnt[tid] = 0;
    __syncthreads();
    for (int e = beg + tid; e < end; e += 256)
        atomicAdd(&hcnt[ebuck[e] >> 24], 1);
    __syncthreads();
    int v = hcnt[tid];
    sc[tid] = v; __syncthreads();
    for (int o = 1; o < 256; o <<= 1) {
        int t = (tid >= o) ? sc[tid - o] : 0;
        __syncthreads();
        sc[tid] += t;
        __syncthreads();
    }
    int excl = sc[tid] - v;
    int n = (b << 8) + tid;
    if (n < N) {
        row_off[n] = beg + excl;
        dinv[n] = rsqrtf((float)(v + 1));   // +1 self loop
    }
    if (b == B - 1 && tid == 0) row_off[N] = E;
    loff[tid] = excl;
    __syncthreads();
    for (int e = beg + tid; e < end; e += 256) {
        unsigned u = ebuck[e];
        int p = atomicAdd(&loff[u >> 24], 1);
        esrc[beg + p] = (int)(u & 0xFFFFFF);
    }
}

// ================= batch (readout segment) preprocessing =================

__global__ void batch_count_kernel(const int* __restrict__ batch, int N, int* __restrict__ gcnt) {
    int i = blockIdx.x * blockDim.x + threadIdx.x;
    if (i < N) atomicAdd(&gcnt[batch[i]], 1);
}

// Exclusive scan of 1024 graph counts in one block; goff[1024] = N
__global__ void gscan_kernel(const int* __restrict__ gcnt, int* __restrict__ goff, int N) {
    __shared__ int sh[1024];
    int tid = threadIdx.x;
    int v = gcnt[tid];
    sh[tid] = v; __syncthreads();
    for (int o = 1; o < 1024; o <<= 1) {
        int t = (tid >= o) ? sh[tid - o] : 0;
        __syncthreads();
        sh[tid] += t;
        __syncthreads();
    }
    goff[tid] = sh[tid] - v;
    if (tid == 1023) goff[1024] = N;
}

// xs[n][f] = x[n][f] * dinv[n]   (vectorized, 16 float4 per 64-wide row)
__global__ void scale_kernel(const float* __restrict__ x, const float* __restrict__ dinv,
                             float* __restrict__ xs, int n4) {
    int i = blockIdx.x * blockDim.x + threadIdx.x;
    if (i < n4) {
        float d = dinv[i >> 4];
        float4 v = ((const float4*)x)[i];
        v.x *= d; v.y *= d; v.z *= d; v.w *= d;
        ((float4*)xs)[i] = v;
    }
}

// ---------------- aggregation: out[n] = dinv[n]*(xs[n] + sum_{e in row(n)} xs[src_e]) (+bias)
// one 64-lane wave per node; lane = feature; 4x unrolled independent gathers
__global__ __launch_bounds__(256) void agg_kernel(const float* __restrict__ xs,
        const int* __restrict__ esrc, const int* __restrict__ row_off,
        const float* __restrict__ dinv, const float* __restrict__ bias,
        float* __restrict__ out, int N) {
    int n = blockIdx.x * 4 + (threadIdx.x >> 6);
    int lane = threadIdx.x & 63;
    if (n >= N) return;
    int beg = row_off[n], end = row_off[n + 1];
    float acc = xs[(size_t)n * 64 + lane];   // self loop term (already dinv-scaled)
    float a0 = 0.f, a1 = 0.f, a2 = 0.f, a3 = 0.f;
    int e = beg;
    for (; e + 4 <= end; e += 4) {
        int s0 = esrc[e], s1 = esrc[e + 1], s2 = esrc[e + 2], s3 = esrc[e + 3];
        a0 += xs[(size_t)s0 * 64 + lane];
        a1 += xs[(size_t)s1 * 64 + lane];
        a2 += xs[(size_t)s2 * 64 + lane];
        a3 += xs[(size_t)s3 * 64 + lane];
    }
    for (; e < end; ++e) acc += xs[(size_t)esrc[e] * 64 + lane];
    acc += (a0 + a1) + (a2 + a3);
    float v = dinv[n] * acc;
    if (bias) v += bias[lane];
    out[(size_t)n * 64 + lane] = v;
}

// ---------------- GEMM1: H[N,128] = relu(A[N,64] @ W[64,128] + b1)
__global__ __launch_bounds__(256) void gemm1_kernel(const float* __restrict__ A,
        const float* __restrict__ W, const float* __restrict__ bias,
        float* __restrict__ H, int N) {
    __shared__ float As[64 * 68];
    __shared__ float Ws[64 * 128];
    int tid = threadIdx.x;
    int m0 = blockIdx.x * 64;
    #pragma unroll
    for (int t = 0; t < 8; ++t) {
        int j = tid + t * 256;
        float4 v = ((const float4*)W)[j];
        *((float4*)&Ws[(j >> 5) * 128 + (j & 31) * 4]) = v;
    }
    #pragma unroll
    for (int t = 0; t < 4; ++t) {
        int j = tid + t * 256;
        int node = j >> 4, c = j & 15;
        int gn = m0 + node;
        float4 v = make_float4(0.f, 0.f, 0.f, 0.f);
        if (gn < N) v = ((const float4*)A)[(size_t)gn * 16 + c];
        *((float4*)&As[node * 68 + c * 4]) = v;
    }
    __syncthreads();
    int tx = tid & 15, ty = tid >> 4;
    float acc[4][8] = {};
    for (int k = 0; k < 64; ++k) {
        float a[4];
        #pragma unroll
        for (int i = 0; i < 4; ++i) a[i] = As[(ty * 4 + i) * 68 + k];
        float4 b0 = *((const float4*)&Ws[k * 128 + tx * 8]);
        float4 b1 = *((const float4*)&Ws[k * 128 + tx * 8 + 4]);
        #pragma unroll
        for (int i = 0; i < 4; ++i) {
            acc[i][0] = fmaf(a[i], b0.x, acc[i][0]);
            acc[i][1] = fmaf(a[i], b0.y, acc[i][1]);
            acc[i][2] = fmaf(a[i], b0.z, acc[i][2]);
            acc[i][3] = fmaf(a[i], b0.w, acc[i][3]);
            acc[i][4] = fmaf(a[i], b1.x, acc[i][4]);
            acc[i][5] = fmaf(a[i], b1.y, acc[i][5]);
            acc[i][6] = fmaf(a[i], b1.z, acc[i][6]);
            acc[i][7] = fmaf(a[i], b1.w, acc[i][7]);
        }
    }
    float4 bb0 = ((const float4*)bias)[tx * 2];
    float4 bb1 = ((const float4*)bias)[tx * 2 + 1];
    #pragma unroll
    for (int i = 0; i < 4; ++i) {
        int n = m0 + ty * 4 + i;
        if (n < N) {
            float4 o0, o1;
            o0.x = fmaxf(acc[i][0] + bb0.x, 0.f);
            o0.y = fmaxf(acc[i][1] + bb0.y, 0.f);
            o0.z = fmaxf(acc[i][2] + bb0.z, 0.f);
            o0.w = fmaxf(acc[i][3] + bb0.w, 0.f);
            o1.x = fmaxf(acc[i][4] + bb1.x, 0.f);
            o1.y = fmaxf(acc[i][5] + bb1.y, 0.f);
            o1.z = fmaxf(acc[i][6] + bb1.z, 0.f);
            o1.w = fmaxf(acc[i][7] + bb1.w, 0.f);
            *((float4*)&H[(size_t)n * 128 + tx * 8]) = o0;
            *((float4*)&H[(size_t)n * 128 + tx * 8 + 4]) = o1;
        }
    }
}

// ---------------- GEMM2: T[N,64] = (H[N,128] @ W2[128,64]) * dinv[n]
__global__ __launch_bounds__(256) void gemm2_kernel(const float* __restrict__ H,
        const float* __restrict__ W, const float* __restrict__ dinv,
        float* __restrict__ T, int N) {
    __shared__ float Hs[64 * 132];
    __shared__ float Ws[128 * 64];
    int tid = threadIdx.x;
    int m0 = blockIdx.x * 64;
    #pragma unroll
    for (int t = 0; t < 8; ++t) {
        int j = tid + t * 256;
        float4 v = ((const float4*)W)[j];
        *((float4*)&Ws[(j >> 4) * 64 + (j & 15) * 4]) = v;
    }
    #pragma unroll
    for (int t = 0; t < 8; ++t) {
        int j = tid + t * 256;
        int node = j >> 5, c = j & 31;
        int gn = m0 + node;
        float4 v = make_float4(0.f, 0.f, 0.f, 0.f);
        if (gn < N) v = ((const float4*)H)[(size_t)gn * 32 + c];
        *((float4*)&Hs[node * 132 + c * 4]) = v;
    }
    __syncthreads();
    int tx = tid & 15, ty = tid >> 4;
    float acc[4][4] = {};
    for (int k = 0; k < 128; ++k) {
        float a[4];
        #pragma unroll
        for (int i = 0; i < 4; ++i) a[i] = Hs[(ty * 4 + i) * 132 + k];
        float4 b = *((const float4*)&Ws[k * 64 + tx * 4]);
        #pragma unroll
        for (int i = 0; i < 4; ++i) {
            acc[i][0] = fmaf(a[i], b.x, acc[i][0]);
            acc[i][1] = fmaf(a[i], b.y, acc[i][1]);
            acc[i][2] = fmaf(a[i], b.z, acc[i][2]);
            acc[i][3] = fmaf(a[i], b.w, acc[i][3]);
        }
    }
    #pragma unroll
    for (int i = 0; i < 4; ++i) {
        int n = m0 + ty * 4 + i;
        if (n < N) {
            float d = dinv[n];
            float4 o;
            o.x = acc[i][0] * d; o.y = acc[i][1] * d;
            o.z = acc[i][2] * d; o.w = acc[i][3] * d;
            *((float4*)&T[(size_t)n * 64 + tx * 4]) = o;
        }
    }
}

// ---------------- readout: r[g] = [mean(h2 rows), max(h2 rows)]  (batch sorted)
__global__ __launch_bounds__(256) void readout_kernel(const float* __restrict__ h2,
        const int* __restrict__ goff, float* __restrict__ r) {
    int g = blockIdx.x;
    int beg = goff[g], end = goff[g + 1];
    int f = threadIdx.x & 63;
    int c = threadIdx.x >> 6;
    float s = 0.f, m = -3.4e38f;
    for (int n = beg + c; n < end; n += 4) {
        float v = h2[(size_t)n * 64 + f];
        s += v;
        m = fmaxf(m, v);
    }
    __shared__ float ss[4][64], sm[4][64];
    ss[c][f] = s; sm[c][f] = m;
    __syncthreads();
    if (c == 0) {
        float S = ss[0][f] + ss[1][f] + ss[2][f] + ss[3][f];
        float M = fmaxf(fmaxf(sm[0][f], sm[1][f]), fmaxf(sm[2][f], sm[3][f]));
        int cnt = end - beg;
        float mean = (cnt > 0) ? S / (float)cnt : 0.f;
        if (cnt == 0) M = 0.f;
        r[(size_t)g * 128 + f] = mean;
        r[(size_t)g * 128 + 64 + f] = M;
    }
}

// ---------------- head: out[g] = r[g] @ Wm + bm   (1024 x 128 @ 128 x 64)
__global__ __launch_bounds__(64) void head_kernel(const float* __restrict__ r,
        const float* __restrict__ Wm, const float* __restrict__ bm,
        float* __restrict__ out) {
    int g = blockIdx.x;
    int j = threadIdx.x;
    float acc = bm[j];
    #pragma unroll 4
    for (int k = 0; k < 128; ++k)
        acc = fmaf(r[(size_t)g * 128 + k], Wm[k * 64 + j], acc);
    out[(size_t)g * 64 + j] = acc;
}

extern "C" void kernel_launch(void* const* d_in, const int* in_sizes, int n_in,
                              void* d_out, int out_size, void* d_ws, size_t ws_size,
                              hipStream_t stream) {
    const float* x    = (const float*)d_in[0];
    const int*  adj   = (const int*)d_in[1];
    const int*  batch = (const int*)d_in[2];
    const float* W1   = (const float*)d_in[3];
    const float* b1   = (const float*)d_in[4];
    const float* W2   = (const float*)d_in[5];
    const float* b2   = (const float*)d_in[6];
    const float* Wm   = (const float*)d_in[7];
    const float* bm   = (const float*)d_in[8];
    float* out = (float*)d_out;

    const int N = in_sizes[0] / 64;
    const int E = in_sizes[1] / 2;
    const int* src = adj;
    const int* dst = adj + E;
    const int B = (N + 255) >> 8;                 // buckets (391)
    const int nblocks = (E + CHUNK - 1) / CHUNK;  // coarse blocks (196)

    // ---- workspace carve (256B aligned) ----
    char* w = (char*)d_ws;
    size_t off = 0;
    auto carve = [&](size_t bytes) -> void* {
        void* p = w + off;
        off += (bytes + 255) & ~(size_t)255;
        return p;
    };
    float* dinv    = (float*)carve((size_t)N * 4);
    int*   row_off = (int*)  carve((size_t)(N + 1) * 4);
    int*   esrc    = (int*)  carve((size_t)E * 4);
    int*   btot    = (int*)  carve((MAXB + 1) * 4);
    int*   bbase   = (int*)  carve((MAXB + 1) * 4);
    int*   gcnt    = (int*)  carve(NGRAPH * 4);
    int*   goff    = (int*)  carve((NGRAPH + 1) * 4);
    float* xs      = (float*)carve((size_t)N * 64 * 4);   // also hosts ebuck (pre-scale), later ts
    float* agg1    = (float*)carve((size_t)N * 64 * 4);   // also hosts cnt (pre-agg), later h2
    float* h1      = (float*)carve((size_t)N * 128 * 4);
    float* r       = (float*)carve((size_t)NGRAPH * 128 * 4);
    unsigned* ebuck = (unsigned*)xs;   // E*4 <= N*64*4, dead before scale_kernel writes xs
    int*      cnt   = (int*)agg1;      // B*nblocks*4 <= N*64*4, dead before agg writes agg1
    float* ts = xs;                    // xs dead after agg1
    float* h2 = agg1;                  // agg1 dead after gemm1

    hipMemsetAsync(btot, 0, (MAXB + 1) * 4, stream);
    hipMemsetAsync(gcnt, 0, NGRAPH * 4, stream);

    // CSR build (two-level bucket sort) + graph segment offsets
    coarse_hist_kernel<<<nblocks, 256, 0, stream>>>(dst, E, nblocks, B, cnt, btot);
    batch_count_kernel<<<(N + 255) / 256, 256, 0, stream>>>(batch, N, gcnt);
    bucket_scan_kernel<<<1, MAXB, 0, stream>>>(btot, bbase, B, E);
    offset_scan_kernel<<<B, 256, 0, stream>>>(cnt, bbase, nblocks);
    coarse_scatter_kernel<<<nblocks, 256, 0, stream>>>(src, dst, E, nblocks, B, cnt, ebuck);
    fine_kernel<<<B, 256, 0, stream>>>(ebuck, bbase, N, E, B, row_off, dinv, esrc);
    gscan_kernel<<<1, 1024, 0, stream>>>(gcnt, goff, N);

    // conv1: xs = x*dinv ; agg1 = dinv*(S+I)xs ; h1 = relu(agg1@W1 + b1)
    scale_kernel<<<(N * 16 + 255) / 256, 256, 0, stream>>>(x, dinv, xs, N * 16);
    agg_kernel<<<(N + 3) / 4, 256, 0, stream>>>(xs, esrc, row_off, dinv, nullptr, agg1, N);
    gemm1_kernel<<<(N + 63) / 64, 256, 0, stream>>>(agg1, W1, b1, h1, N);

    // conv2: ts = (h1@W2)*dinv ; h2 = dinv*(S+I)ts + b2
    gemm2_kernel<<<(N + 63) / 64, 256, 0, stream>>>(h1, W2, dinv, ts, N);
    agg_kernel<<<(N + 3) / 4, 256, 0, stream>>>(ts, esrc, row_off, dinv, b2, h2, N);

    // readout + head
    readout_kernel<<<NGRAPH, 256, 0, stream>>>(h2, goff, r);
    head_kernel<<<NGRAPH, 64, 0, stream>>>(r, Wm, bm, out);
}

// Round 4
// 457.502 us; speedup vs baseline: 1.9178x; 1.2010x over previous
//
#include <hip/hip_runtime.h>
#include <hip/hip_fp16.h>
#include <cstdint>
#include <cstddef>

// Problem constants (from reference): N=100000, F_IN=64, F1=128, F2=64,
// E=3200000, NUM_GRAPHS=1024. N and E derived from in_sizes at launch.
#define NGRAPH 1024
#define CHUNK 16384      // edges per block in coarse pass
#define MAXB 512         // max buckets (supports N <= 131072; here B=391)

// ================= two-level bucket CSR build =================
// bucket b = dst >> 8. Edge word packs (dst & 255) << 24 | src (src < 2^24).

__global__ __launch_bounds__(256) void coarse_hist_kernel(const int* __restrict__ dst,
        int E, int nblocks, int B, int* __restrict__ cnt, int* __restrict__ btot) {
    __shared__ int h[MAXB];
    int blk = blockIdx.x, tid = threadIdx.x;
    for (int i = tid; i < B; i += 256) h[i] = 0;
    __syncthreads();
    int base = blk * CHUNK;
    #pragma unroll 4
    for (int it = 0; it < CHUNK / 256; ++it) {
        int i = base + tid + it * 256;
        if (i < E) atomicAdd(&h[dst[i] >> 8], 1);
    }
    __syncthreads();
    for (int b = tid; b < B; b += 256) {
        int c = h[b];
        cnt[b * nblocks + blk] = c;
        if (c) atomicAdd(&btot[b], c);
    }
}

__global__ void bucket_scan_kernel(const int* __restrict__ btot, int* __restrict__ bbase,
                                   int B, int E) {
    __shared__ int sh[MAXB];
    int tid = threadIdx.x;
    int v = (tid < B) ? btot[tid] : 0;
    sh[tid] = v; __syncthreads();
    for (int o = 1; o < MAXB; o <<= 1) {
        int t = (tid >= o) ? sh[tid - o] : 0;
        __syncthreads();
        sh[tid] += t;
        __syncthreads();
    }
    if (tid < B) bbase[tid] = sh[tid] - v;
    if (tid == 0) bbase[B] = E;
}

__global__ __launch_bounds__(256) void offset_scan_kernel(int* __restrict__ cnt,
        const int* __restrict__ bbase, int nblocks) {
    __shared__ int sh[256];
    int b = blockIdx.x, tid = threadIdx.x;
    int v = (tid < nblocks) ? cnt[b * nblocks + tid] : 0;
    sh[tid] = v; __syncthreads();
    for (int o = 1; o < 256; o <<= 1) {
        int t = (tid >= o) ? sh[tid - o] : 0;
        __syncthreads();
        sh[tid] += t;
        __syncthreads();
    }
    if (tid < nblocks) cnt[b * nblocks + tid] = sh[tid] - v + bbase[b];
}

__global__ __launch_bounds__(256) void coarse_scatter_kernel(const int* __restrict__ src,
        const int* __restrict__ dst, int E, int nblocks, int B,
        const int* __restrict__ cnt, unsigned* __restrict__ ebuck) {
    __shared__ int loff[MAXB];
    int blk = blockIdx.x, tid = threadIdx.x;
    for (int b = tid; b < B; b += 256) loff[b] = cnt[b * nblocks + blk];
    __syncthreads();
    int base = blk * CHUNK;
    #pragma unroll 4
    for (int it = 0; it < CHUNK / 256; ++it) {
        int i = base + tid + it * 256;
        if (i < E) {
            int d = dst[i], s = src[i];
            int p = atomicAdd(&loff[d >> 8], 1);
            ebuck[p] = ((unsigned)(d & 255) << 24) | (unsigned)s;
        }
    }
}

__global__ __launch_bounds__(256) void fine_kernel(const unsigned* __restrict__ ebuck,
        const int* __restrict__ bbase, int N, int E, int B,
        int* __restrict__ row_off, float* __restrict__ dinv, int* __restrict__ esrc) {
    __shared__ int hcnt[256];
    __shared__ int sc[256];
    __shared__ int loff[256];
    int b = blockIdx.x, tid = threadIdx.x;
    int beg = bbase[b], end = bbase[b + 1];
    hcnt[tid] = 0;
    __syncthreads();
    for (int e = beg + tid; e < end; e += 256)
        atomicAdd(&hcnt[ebuck[e] >> 24], 1);
    __syncthreads();
    int v = hcnt[tid];
    sc[tid] = v; __syncthreads();
    for (int o = 1; o < 256; o <<= 1) {
        int t = (tid >= o) ? sc[tid - o] : 0;
        __syncthreads();
        sc[tid] += t;
        __syncthreads();
    }
    int excl = sc[tid] - v;
    int n = (b << 8) + tid;
    if (n < N) {
        row_off[n] = beg + excl;
        dinv[n] = rsqrtf((float)(v + 1));   // +1 self loop
    }
    if (b == B - 1 && tid == 0) row_off[N] = E;
    loff[tid] = excl;
    __syncthreads();
    for (int e = beg + tid; e < end; e += 256) {
        unsigned u = ebuck[e];
        int p = atomicAdd(&loff[u >> 24], 1);
        esrc[beg + p] = (int)(u & 0xFFFFFF);
    }
}

// ================= batch (readout segment) preprocessing =================

__global__ void batch_count_kernel(const int* __restrict__ batch, int N, int* __restrict__ gcnt) {
    int i = blockIdx.x * blockDim.x + threadIdx.x;
    if (i < N) atomicAdd(&gcnt[batch[i]], 1);
}

__global__ void gscan_kernel(const int* __restrict__ gcnt, int* __restrict__ goff, int N) {
    __shared__ int sh[1024];
    int tid = threadIdx.x;
    int v = gcnt[tid];
    sh[tid] = v; __syncthreads();
    for (int o = 1; o < 1024; o <<= 1) {
        int t = (tid >= o) ? sh[tid - o] : 0;
        __syncthreads();
        sh[tid] += t;
        __syncthreads();
    }
    goff[tid] = sh[tid] - v;
    if (tid == 1023) goff[1024] = N;
}

// pack: xs_h[n][f] = half(x[n][f] * dinv[n])  (one float4 -> 4 halfs per thread)
__global__ void pack_kernel(const float* __restrict__ x, const float* __restrict__ dinv,
                            __half* __restrict__ xs, int n4) {
    int i = blockIdx.x * blockDim.x + threadIdx.x;
    if (i < n4) {
        float d = dinv[i >> 4];
        float4 v = ((const float4*)x)[i];
        __half2 h0 = __floats2half2_rn(v.x * d, v.y * d);
        __half2 h1 = __floats2half2_rn(v.z * d, v.w * d);
        uint2 u;
        u.x = *(unsigned*)&h0;
        u.y = *(unsigned*)&h1;
        ((uint2*)xs)[i] = u;
    }
}

// ---------------- aggregation (fp16 gather, fp32 accumulate) ----------------
// out[n] = dinv[n]*(xs[n] + sum_{e in row(n)} xs[src_e]) (+bias)
// 64-lane wave per node: 4 groups x 16 lanes; group g gathers edge slot g,
// lane chunk c covers features c*4..c*4+3 (uint2 = 4 halfs). 2-deep unroll
// -> 8 gathers in flight per wave. Cross-group reduce: shfl_xor 16,32.
__global__ __launch_bounds__(256) void agg_h_kernel(const __half* __restrict__ xs,
        const int* __restrict__ esrc, const int* __restrict__ row_off,
        const float* __restrict__ dinv, const float* __restrict__ bias,
        float* __restrict__ out, int N) {
    int n = blockIdx.x * 4 + (threadIdx.x >> 6);
    if (n >= N) return;
    int lane = threadIdx.x & 63;
    int g = lane >> 4, c = lane & 15;
    const uint2* xs2 = (const uint2*)xs;   // row stride 16 uint2
    int beg = row_off[n], end = row_off[n + 1];
    float4 acc = make_float4(0.f, 0.f, 0.f, 0.f);
    float4 acc2 = make_float4(0.f, 0.f, 0.f, 0.f);

    if (g == 0) {   // self-loop term
        uint2 u = xs2[(size_t)n * 16 + c];
        __half2 h0 = *(__half2*)&u.x, h1 = *(__half2*)&u.y;
        float2 f0 = __half22float2(h0), f1 = __half22float2(h1);
        acc.x += f0.x; acc.y += f0.y; acc.z += f1.x; acc.w += f1.y;
    }
    int e = beg + g;
    for (; e + 4 < end; e += 8) {
        int s0 = esrc[e], s1 = esrc[e + 4];
        uint2 u0 = xs2[(size_t)s0 * 16 + c];
        uint2 u1 = xs2[(size_t)s1 * 16 + c];
        float2 a0 = __half22float2(*(__half2*)&u0.x), a1 = __half22float2(*(__half2*)&u0.y);
        float2 b0 = __half22float2(*(__half2*)&u1.x), b1 = __half22float2(*(__half2*)&u1.y);
        acc.x += a0.x;  acc.y += a0.y;  acc.z += a1.x;  acc.w += a1.y;
        acc2.x += b0.x; acc2.y += b0.y; acc2.z += b1.x; acc2.w += b1.y;
    }
    if (e < end) {
        uint2 u = xs2[(size_t)esrc[e] * 16 + c];
        float2 f0 = __half22float2(*(__half2*)&u.x), f1 = __half22float2(*(__half2*)&u.y);
        acc.x += f0.x; acc.y += f0.y; acc.z += f1.x; acc.w += f1.y;
    }
    acc.x += acc2.x; acc.y += acc2.y; acc.z += acc2.z; acc.w += acc2.w;
    // reduce across the 4 groups (lane bits 4 and 5); c is preserved
    acc.x += __shfl_xor(acc.x, 16, 64);
    acc.y += __shfl_xor(acc.y, 16, 64);
    acc.z += __shfl_xor(acc.z, 16, 64);
    acc.w += __shfl_xor(acc.w, 16, 64);
    acc.x += __shfl_xor(acc.x, 32, 64);
    acc.y += __shfl_xor(acc.y, 32, 64);
    acc.z += __shfl_xor(acc.z, 32, 64);
    acc.w += __shfl_xor(acc.w, 32, 64);
    if (g == 0) {
        float d = dinv[n];
        float4 o;
        o.x = acc.x * d; o.y = acc.y * d; o.z = acc.z * d; o.w = acc.w * d;
        if (bias) {
            float4 bb = ((const float4*)bias)[c];
            o.x += bb.x; o.y += bb.y; o.z += bb.z; o.w += bb.w;
        }
        ((float4*)out)[(size_t)n * 16 + c] = o;
    }
}

// ---------------- GEMM1: H[N,128] = relu(A[N,64] @ W[64,128] + b1)
__global__ __launch_bounds__(256) void gemm1_kernel(const float* __restrict__ A,
        const float* __restrict__ W, const float* __restrict__ bias,
        float* __restrict__ H, int N) {
    __shared__ float As[64 * 68];
    __shared__ float Ws[64 * 128];
    int tid = threadIdx.x;
    int m0 = blockIdx.x * 64;
    #pragma unroll
    for (int t = 0; t < 8; ++t) {
        int j = tid + t * 256;
        float4 v = ((const float4*)W)[j];
        *((float4*)&Ws[(j >> 5) * 128 + (j & 31) * 4]) = v;
    }
    #pragma unroll
    for (int t = 0; t < 4; ++t) {
        int j = tid + t * 256;
        int node = j >> 4, c = j & 15;
        int gn = m0 + node;
        float4 v = make_float4(0.f, 0.f, 0.f, 0.f);
        if (gn < N) v = ((const float4*)A)[(size_t)gn * 16 + c];
        *((float4*)&As[node * 68 + c * 4]) = v;
    }
    __syncthreads();
    int tx = tid & 15, ty = tid >> 4;
    float acc[4][8] = {};
    for (int k = 0; k < 64; ++k) {
        float a[4];
        #pragma unroll
        for (int i = 0; i < 4; ++i) a[i] = As[(ty * 4 + i) * 68 + k];
        float4 b0 = *((const float4*)&Ws[k * 128 + tx * 8]);
        float4 b1 = *((const float4*)&Ws[k * 128 + tx * 8 + 4]);
        #pragma unroll
        for (int i = 0; i < 4; ++i) {
            acc[i][0] = fmaf(a[i], b0.x, acc[i][0]);
            acc[i][1] = fmaf(a[i], b0.y, acc[i][1]);
            acc[i][2] = fmaf(a[i], b0.z, acc[i][2]);
            acc[i][3] = fmaf(a[i], b0.w, acc[i][3]);
            acc[i][4] = fmaf(a[i], b1.x, acc[i][4]);
            acc[i][5] = fmaf(a[i], b1.y, acc[i][5]);
            acc[i][6] = fmaf(a[i], b1.z, acc[i][6]);
            acc[i][7] = fmaf(a[i], b1.w, acc[i][7]);
        }
    }
    float4 bb0 = ((const float4*)bias)[tx * 2];
    float4 bb1 = ((const float4*)bias)[tx * 2 + 1];
    #pragma unroll
    for (int i = 0; i < 4; ++i) {
        int n = m0 + ty * 4 + i;
        if (n < N) {
            float4 o0, o1;
            o0.x = fmaxf(acc[i][0] + bb0.x, 0.f);
            o0.y = fmaxf(acc[i][1] + bb0.y, 0.f);
            o0.z = fmaxf(acc[i][2] + bb0.z, 0.f);
            o0.w = fmaxf(acc[i][3] + bb0.w, 0.f);
            o1.x = fmaxf(acc[i][4] + bb1.x, 0.f);
            o1.y = fmaxf(acc[i][5] + bb1.y, 0.f);
            o1.z = fmaxf(acc[i][6] + bb1.z, 0.f);
            o1.w = fmaxf(acc[i][7] + bb1.w, 0.f);
            *((float4*)&H[(size_t)n * 128 + tx * 8]) = o0;
            *((float4*)&H[(size_t)n * 128 + tx * 8 + 4]) = o1;
        }
    }
}

// ---------------- GEMM2: T_h[N,64] = half((H[N,128] @ W2[128,64]) * dinv[n])
__global__ __launch_bounds__(256) void gemm2_kernel(const float* __restrict__ H,
        const float* __restrict__ W, const float* __restrict__ dinv,
        __half* __restrict__ T, int N) {
    __shared__ float Hs[64 * 132];
    __shared__ float Ws[128 * 64];
    int tid = threadIdx.x;
    int m0 = blockIdx.x * 64;
    #pragma unroll
    for (int t = 0; t < 8; ++t) {
        int j = tid + t * 256;
        float4 v = ((const float4*)W)[j];
        *((float4*)&Ws[(j >> 4) * 64 + (j & 15) * 4]) = v;
    }
    #pragma unroll
    for (int t = 0; t < 8; ++t) {
        int j = tid + t * 256;
        int node = j >> 5, c = j & 31;
        int gn = m0 + node;
        float4 v = make_float4(0.f, 0.f, 0.f, 0.f);
        if (gn < N) v = ((const float4*)H)[(size_t)gn * 32 + c];
        *((float4*)&Hs[node * 132 + c * 4]) = v;
    }
    __syncthreads();
    int tx = tid & 15, ty = tid >> 4;
    float acc[4][4] = {};
    for (int k = 0; k < 128; ++k) {
        float a[4];
        #pragma unroll
        for (int i = 0; i < 4; ++i) a[i] = Hs[(ty * 4 + i) * 132 + k];
        float4 b = *((const float4*)&Ws[k * 64 + tx * 4]);
        #pragma unroll
        for (int i = 0; i < 4; ++i) {
            acc[i][0] = fmaf(a[i], b.x, acc[i][0]);
            acc[i][1] = fmaf(a[i], b.y, acc[i][1]);
            acc[i][2] = fmaf(a[i], b.z, acc[i][2]);
            acc[i][3] = fmaf(a[i], b.w, acc[i][3]);
        }
    }
    #pragma unroll
    for (int i = 0; i < 4; ++i) {
        int n = m0 + ty * 4 + i;
        if (n < N) {
            float d = dinv[n];
            __half2 h0 = __floats2half2_rn(acc[i][0] * d, acc[i][1] * d);
            __half2 h1 = __floats2half2_rn(acc[i][2] * d, acc[i][3] * d);
            uint2 u;
            u.x = *(unsigned*)&h0;
            u.y = *(unsigned*)&h1;
            ((uint2*)T)[(size_t)n * 16 + tx] = u;
        }
    }
}

// ---------------- readout: r[g] = [mean(h2 rows), max(h2 rows)]  (batch sorted)
__global__ __launch_bounds__(256) void readout_kernel(const float* __restrict__ h2,
        const int* __restrict__ goff, float* __restrict__ r) {
    int g = blockIdx.x;
    int beg = goff[g], end = goff[g + 1];
    int f = threadIdx.x & 63;
    int c = threadIdx.x >> 6;
    float s = 0.f, m = -3.4e38f;
    for (int n = beg + c; n < end; n += 4) {
        float v = h2[(size_t)n * 64 + f];
        s += v;
        m = fmaxf(m, v);
    }
    __shared__ float ss[4][64], sm[4][64];
    ss[c][f] = s; sm[c][f] = m;
    __syncthreads();
    if (c == 0) {
        float S = ss[0][f] + ss[1][f] + ss[2][f] + ss[3][f];
        float M = fmaxf(fmaxf(sm[0][f], sm[1][f]), fmaxf(sm[2][f], sm[3][f]));
        int cnt = end - beg;
        float mean = (cnt > 0) ? S / (float)cnt : 0.f;
        if (cnt == 0) M = 0.f;
        r[(size_t)g * 128 + f] = mean;
        r[(size_t)g * 128 + 64 + f] = M;
    }
}

// ---------------- head: out[g] = r[g] @ Wm + bm   (1024 x 128 @ 128 x 64)
__global__ __launch_bounds__(64) void head_kernel(const float* __restrict__ r,
        const float* __restrict__ Wm, const float* __restrict__ bm,
        float* __restrict__ out) {
    int g = blockIdx.x;
    int j = threadIdx.x;
    float acc = bm[j];
    #pragma unroll 4
    for (int k = 0; k < 128; ++k)
        acc = fmaf(r[(size_t)g * 128 + k], Wm[k * 64 + j], acc);
    out[(size_t)g * 64 + j] = acc;
}

extern "C" void kernel_launch(void* const* d_in, const int* in_sizes, int n_in,
                              void* d_out, int out_size, void* d_ws, size_t ws_size,
                              hipStream_t stream) {
    const float* x    = (const float*)d_in[0];
    const int*  adj   = (const int*)d_in[1];
    const int*  batch = (const int*)d_in[2];
    const float* W1   = (const float*)d_in[3];
    const float* b1   = (const float*)d_in[4];
    const float* W2   = (const float*)d_in[5];
    const float* b2   = (const float*)d_in[6];
    const float* Wm   = (const float*)d_in[7];
    const float* bm   = (const float*)d_in[8];
    float* out = (float*)d_out;

    const int N = in_sizes[0] / 64;
    const int E = in_sizes[1] / 2;
    const int* src = adj;
    const int* dst = adj + E;
    const int B = (N + 255) >> 8;                 // buckets (391)
    const int nblocks = (E + CHUNK - 1) / CHUNK;  // coarse blocks (196)

    // ---- workspace carve (256B aligned) ----
    char* w = (char*)d_ws;
    size_t off = 0;
    auto carve = [&](size_t bytes) -> void* {
        void* p = w + off;
        off += (bytes + 255) & ~(size_t)255;
        return p;
    };
    size_t halfbuf = (size_t)N * 64 * 2;
    size_t ebbytes = (size_t)E * 4;
    float* dinv    = (float*)carve((size_t)N * 4);
    int*   row_off = (int*)  carve((size_t)(N + 1) * 4);
    int*   esrc    = (int*)  carve((size_t)E * 4);
    int*   btot    = (int*)  carve((MAXB + 1) * 4);
    int*   bbase   = (int*)  carve((MAXB + 1) * 4);
    int*   gcnt    = (int*)  carve(NGRAPH * 4);
    int*   goff    = (int*)  carve((NGRAPH + 1) * 4);
    __half* xs_h   = (__half*)carve(halfbuf > ebbytes ? halfbuf : ebbytes); // also hosts ebuck pre-pack; later ts_h
    float* agg1    = (float*)carve((size_t)N * 64 * 4);   // also hosts cnt pre-agg; later h2
    float* h1      = (float*)carve((size_t)N * 128 * 4);
    float* r       = (float*)carve((size_t)NGRAPH * 128 * 4);
    unsigned* ebuck = (unsigned*)xs_h; // dead before pack_kernel writes xs_h
    int*      cnt   = (int*)agg1;      // dead before agg writes agg1
    __half* ts_h = xs_h;               // xs_h dead after first agg
    float* h2 = agg1;                  // agg1 dead after gemm1

    hipMemsetAsync(btot, 0, (MAXB + 1) * 4, stream);
    hipMemsetAsync(gcnt, 0, NGRAPH * 4, stream);

    // CSR build (two-level bucket sort) + graph segment offsets
    coarse_hist_kernel<<<nblocks, 256, 0, stream>>>(dst, E, nblocks, B, cnt, btot);
    batch_count_kernel<<<(N + 255) / 256, 256, 0, stream>>>(batch, N, gcnt);
    bucket_scan_kernel<<<1, MAXB, 0, stream>>>(btot, bbase, B, E);
    offset_scan_kernel<<<B, 256, 0, stream>>>(cnt, bbase, nblocks);
    coarse_scatter_kernel<<<nblocks, 256, 0, stream>>>(src, dst, E, nblocks, B, cnt, ebuck);
    fine_kernel<<<B, 256, 0, stream>>>(ebuck, bbase, N, E, B, row_off, dinv, esrc);
    gscan_kernel<<<1, 1024, 0, stream>>>(gcnt, goff, N);

    // conv1: xs_h = half(x*dinv) ; agg1 = dinv*(S+I)xs ; h1 = relu(agg1@W1 + b1)
    pack_kernel<<<(N * 16 + 255) / 256, 256, 0, stream>>>(x, dinv, xs_h, N * 16);
    agg_h_kernel<<<(N + 3) / 4, 256, 0, stream>>>(xs_h, esrc, row_off, dinv, nullptr, agg1, N);
    gemm1_kernel<<<(N + 63) / 64, 256, 0, stream>>>(agg1, W1, b1, h1, N);

    // conv2: ts_h = half((h1@W2)*dinv) ; h2 = dinv*(S+I)ts + b2
    gemm2_kernel<<<(N + 63) / 64, 256, 0, stream>>>(h1, W2, dinv, ts_h, N);
    agg_h_kernel<<<(N + 3) / 4, 256, 0, stream>>>(ts_h, esrc, row_off, dinv, b2, h2, N);

    // readout + head
    readout_kernel<<<NGRAPH, 256, 0, stream>>>(h2, goff, r);
    head_kernel<<<NGRAPH, 64, 0, stream>>>(r, Wm, bm, out);
}

// Round 5
// 414.268 us; speedup vs baseline: 2.1179x; 1.1044x over previous
//
#include <hip/hip_runtime.h>
#include <hip/hip_fp16.h>
#include <cstdint>
#include <cstddef>

// Problem constants (from reference): N=100000, F_IN=64, F1=128, F2=64,
// E=3200000, NUM_GRAPHS=1024. N and E derived from in_sizes at launch.
#define NGRAPH 1024
#define CHUNK 16384      // edges per block in coarse pass
#define MAXB 512         // max buckets (supports N <= 131072; here B=391)

typedef _Float16 f16x8 __attribute__((ext_vector_type(8)));
typedef float f32x4 __attribute__((ext_vector_type(4)));

// ================= two-level bucket CSR build =================
// bucket b = dst >> 8. Edge word packs (dst & 255) << 24 | src (src < 2^24).

__global__ __launch_bounds__(256) void coarse_hist_kernel(const int* __restrict__ dst,
        int E, int nblocks, int B, int* __restrict__ cnt, int* __restrict__ btot) {
    __shared__ int h[MAXB];
    int blk = blockIdx.x, tid = threadIdx.x;
    for (int i = tid; i < B; i += 256) h[i] = 0;
    __syncthreads();
    int base = blk * CHUNK;
    #pragma unroll 4
    for (int it = 0; it < CHUNK / 256; ++it) {
        int i = base + tid + it * 256;
        if (i < E) atomicAdd(&h[dst[i] >> 8], 1);
    }
    __syncthreads();
    for (int b = tid; b < B; b += 256) {
        int c = h[b];
        cnt[b * nblocks + blk] = c;
        if (c) atomicAdd(&btot[b], c);
    }
}

__global__ void bucket_scan_kernel(const int* __restrict__ btot, int* __restrict__ bbase,
                                   int B, int E) {
    __shared__ int sh[MAXB];
    int tid = threadIdx.x;
    int v = (tid < B) ? btot[tid] : 0;
    sh[tid] = v; __syncthreads();
    for (int o = 1; o < MAXB; o <<= 1) {
        int t = (tid >= o) ? sh[tid - o] : 0;
        __syncthreads();
        sh[tid] += t;
        __syncthreads();
    }
    if (tid < B) bbase[tid] = sh[tid] - v;
    if (tid == 0) bbase[B] = E;
}

__global__ __launch_bounds__(256) void offset_scan_kernel(int* __restrict__ cnt,
        const int* __restrict__ bbase, int nblocks) {
    __shared__ int sh[256];
    int b = blockIdx.x, tid = threadIdx.x;
    int v = (tid < nblocks) ? cnt[b * nblocks + tid] : 0;
    sh[tid] = v; __syncthreads();
    for (int o = 1; o < 256; o <<= 1) {
        int t = (tid >= o) ? sh[tid - o] : 0;
        __syncthreads();
        sh[tid] += t;
        __syncthreads();
    }
    if (tid < nblocks) cnt[b * nblocks + tid] = sh[tid] - v + bbase[b];
}

__global__ __launch_bounds__(256) void coarse_scatter_kernel(const int* __restrict__ src,
        const int* __restrict__ dst, int E, int nblocks, int B,
        const int* __restrict__ cnt, unsigned* __restrict__ ebuck) {
    __shared__ int loff[MAXB];
    int blk = blockIdx.x, tid = threadIdx.x;
    for (int b = tid; b < B; b += 256) loff[b] = cnt[b * nblocks + blk];
    __syncthreads();
    int base = blk * CHUNK;
    #pragma unroll 4
    for (int it = 0; it < CHUNK / 256; ++it) {
        int i = base + tid + it * 256;
        if (i < E) {
            int d = dst[i], s = src[i];
            int p = atomicAdd(&loff[d >> 8], 1);
            ebuck[p] = ((unsigned)(d & 255) << 24) | (unsigned)s;
        }
    }
}

__global__ __launch_bounds__(256) void fine_kernel(const unsigned* __restrict__ ebuck,
        const int* __restrict__ bbase, int N, int E, int B,
        int* __restrict__ row_off, float* __restrict__ dinv, int* __restrict__ esrc) {
    __shared__ int hcnt[256];
    __shared__ int sc[256];
    __shared__ int loff[256];
    int b = blockIdx.x, tid = threadIdx.x;
    int beg = bbase[b], end = bbase[b + 1];
    hcnt[tid] = 0;
    __syncthreads();
    for (int e = beg + tid; e < end; e += 256)
        atomicAdd(&hcnt[ebuck[e] >> 24], 1);
    __syncthreads();
    int v = hcnt[tid];
    sc[tid] = v; __syncthreads();
    for (int o = 1; o < 256; o <<= 1) {
        int t = (tid >= o) ? sc[tid - o] : 0;
        __syncthreads();
        sc[tid] += t;
        __syncthreads();
    }
    int excl = sc[tid] - v;
    int n = (b << 8) + tid;
    if (n < N) {
        row_off[n] = beg + excl;
        dinv[n] = rsqrtf((float)(v + 1));   // +1 self loop
    }
    if (b == B - 1 && tid == 0) row_off[N] = E;
    loff[tid] = excl;
    __syncthreads();
    for (int e = beg + tid; e < end; e += 256) {
        unsigned u = ebuck[e];
        int p = atomicAdd(&loff[u >> 24], 1);
        esrc[beg + p] = (int)(u & 0xFFFFFF);
    }
}

// ================= batch (readout segment) preprocessing =================

__global__ void batch_count_kernel(const int* __restrict__ batch, int N, int* __restrict__ gcnt) {
    int i = blockIdx.x * blockDim.x + threadIdx.x;
    if (i < N) atomicAdd(&gcnt[batch[i]], 1);
}

__global__ void gscan_kernel(const int* __restrict__ gcnt, int* __restrict__ goff, int N) {
    __shared__ int sh[1024];
    int tid = threadIdx.x;
    int v = gcnt[tid];
    sh[tid] = v; __syncthreads();
    for (int o = 1; o < 1024; o <<= 1) {
        int t = (tid >= o) ? sh[tid - o] : 0;
        __syncthreads();
        sh[tid] += t;
        __syncthreads();
    }
    goff[tid] = sh[tid] - v;
    if (tid == 1023) goff[1024] = N;
}

// pack: xs_h[n][f] = half(x[n][f] * dinv[n])
__global__ void pack_kernel(const float* __restrict__ x, const float* __restrict__ dinv,
                            __half* __restrict__ xs, int n4) {
    int i = blockIdx.x * blockDim.x + threadIdx.x;
    if (i < n4) {
        float d = dinv[i >> 4];
        float4 v = ((const float4*)x)[i];
        __half2 h0 = __floats2half2_rn(v.x * d, v.y * d);
        __half2 h1 = __floats2half2_rn(v.z * d, v.w * d);
        uint2 u;
        u.x = *(unsigned*)&h0;
        u.y = *(unsigned*)&h1;
        ((uint2*)xs)[i] = u;
    }
}

// ---------------- weight pre-swizzle: frag-linear fp16 layouts ----------------
// W1s slot s = ((ks*8+nt)*4+q)*16+n  -> 8 halfs W1[ks*32+q*8+j][nt*16+n]
// W2s slot s = ((ks2*4+n2)*4+q)*16+n -> 8 halfs W2[ks2*32+q*8+j][n2*16+n]
__global__ __launch_bounds__(256) void wconv_kernel(const float* __restrict__ W1,
        const float* __restrict__ W2, __half* __restrict__ W1s, __half* __restrict__ W2s) {
    int t = threadIdx.x;
    #pragma unroll
    for (int it = 0; it < 4; ++it) {
        int s = t + it * 256;
        int n = s & 15, q = (s >> 4) & 3, nt = (s >> 6) & 7, ks = s >> 9;
        int k0 = ks * 32 + q * 8, col = nt * 16 + n;
        __align__(16) __half h[8];
        #pragma unroll
        for (int j = 0; j < 8; ++j) h[j] = (__half)W1[(k0 + j) * 128 + col];
        *((uint4*)&W1s[(size_t)s * 8]) = *(uint4*)h;
    }
    #pragma unroll
    for (int it = 0; it < 4; ++it) {
        int s = t + it * 256;
        int n = s & 15, q = (s >> 4) & 3, n2 = (s >> 6) & 3, ks2 = s >> 8;
        int k0 = ks2 * 32 + q * 8, col = n2 * 16 + n;
        __align__(16) __half h[8];
        #pragma unroll
        for (int j = 0; j < 8; ++j) h[j] = (__half)W2[(k0 + j) * 64 + col];
        *((uint4*)&W2s[(size_t)s * 8]) = *(uint4*)h;
    }
}

// ---------------- aggregation (fp16 gather, fp32 accumulate) ----------------
// 64-lane wave per node: 4 groups x 16 lanes; group g gathers edge slot g,
// lane chunk c covers features c*4..c*4+3. Cross-group reduce: shfl_xor 16,32.
// Variant 1: fp16 output, no bias (conv1 -> feeds MFMA GEMM)
__global__ __launch_bounds__(256) void agg_h2h_kernel(const __half* __restrict__ xs,
        const int* __restrict__ esrc, const int* __restrict__ row_off,
        const float* __restrict__ dinv, __half* __restrict__ out, int N) {
    int n = blockIdx.x * 4 + (threadIdx.x >> 6);
    if (n >= N) return;
    int lane = threadIdx.x & 63;
    int g = lane >> 4, c = lane & 15;
    const uint2* xs2 = (const uint2*)xs;
    int beg = row_off[n], end = row_off[n + 1];
    float4 acc = make_float4(0.f, 0.f, 0.f, 0.f);
    float4 acc2 = make_float4(0.f, 0.f, 0.f, 0.f);
    if (g == 0) {
        uint2 u = xs2[(size_t)n * 16 + c];
        float2 f0 = __half22float2(*(__half2*)&u.x), f1 = __half22float2(*(__half2*)&u.y);
        acc.x += f0.x; acc.y += f0.y; acc.z += f1.x; acc.w += f1.y;
    }
    int e = beg + g;
    for (; e + 4 < end; e += 8) {
        int s0 = esrc[e], s1 = esrc[e + 4];
        uint2 u0 = xs2[(size_t)s0 * 16 + c];
        uint2 u1 = xs2[(size_t)s1 * 16 + c];
        float2 a0 = __half22float2(*(__half2*)&u0.x), a1 = __half22float2(*(__half2*)&u0.y);
        float2 b0 = __half22float2(*(__half2*)&u1.x), b1 = __half22float2(*(__half2*)&u1.y);
        acc.x += a0.x;  acc.y += a0.y;  acc.z += a1.x;  acc.w += a1.y;
        acc2.x += b0.x; acc2.y += b0.y; acc2.z += b1.x; acc2.w += b1.y;
    }
    if (e < end) {
        uint2 u = xs2[(size_t)esrc[e] * 16 + c];
        float2 f0 = __half22float2(*(__half2*)&u.x), f1 = __half22float2(*(__half2*)&u.y);
        acc.x += f0.x; acc.y += f0.y; acc.z += f1.x; acc.w += f1.y;
    }
    acc.x += acc2.x; acc.y += acc2.y; acc.z += acc2.z; acc.w += acc2.w;
    acc.x += __shfl_xor(acc.x, 16, 64); acc.y += __shfl_xor(acc.y, 16, 64);
    acc.z += __shfl_xor(acc.z, 16, 64); acc.w += __shfl_xor(acc.w, 16, 64);
    acc.x += __shfl_xor(acc.x, 32, 64); acc.y += __shfl_xor(acc.y, 32, 64);
    acc.z += __shfl_xor(acc.z, 32, 64); acc.w += __shfl_xor(acc.w, 32, 64);
    if (g == 0) {
        float d = dinv[n];
        __half2 h0 = __floats2half2_rn(acc.x * d, acc.y * d);
        __half2 h1 = __floats2half2_rn(acc.z * d, acc.w * d);
        uint2 u;
        u.x = *(unsigned*)&h0;
        u.y = *(unsigned*)&h1;
        ((uint2*)out)[(size_t)n * 16 + c] = u;
    }
}

// Variant 2: fp32 output + bias (conv2 -> feeds readout)
__global__ __launch_bounds__(256) void agg_h2f_kernel(const __half* __restrict__ xs,
        const int* __restrict__ esrc, const int* __restrict__ row_off,
        const float* __restrict__ dinv, const float* __restrict__ bias,
        float* __restrict__ out, int N) {
    int n = blockIdx.x * 4 + (threadIdx.x >> 6);
    if (n >= N) return;
    int lane = threadIdx.x & 63;
    int g = lane >> 4, c = lane & 15;
    const uint2* xs2 = (const uint2*)xs;
    int beg = row_off[n], end = row_off[n + 1];
    float4 acc = make_float4(0.f, 0.f, 0.f, 0.f);
    float4 acc2 = make_float4(0.f, 0.f, 0.f, 0.f);
    if (g == 0) {
        uint2 u = xs2[(size_t)n * 16 + c];
        float2 f0 = __half22float2(*(__half2*)&u.x), f1 = __half22float2(*(__half2*)&u.y);
        acc.x += f0.x; acc.y += f0.y; acc.z += f1.x; acc.w += f1.y;
    }
    int e = beg + g;
    for (; e + 4 < end; e += 8) {
        int s0 = esrc[e], s1 = esrc[e + 4];
        uint2 u0 = xs2[(size_t)s0 * 16 + c];
        uint2 u1 = xs2[(size_t)s1 * 16 + c];
        float2 a0 = __half22float2(*(__half2*)&u0.x), a1 = __half22float2(*(__half2*)&u0.y);
        float2 b0 = __half22float2(*(__half2*)&u1.x), b1 = __half22float2(*(__half2*)&u1.y);
        acc.x += a0.x;  acc.y += a0.y;  acc.z += a1.x;  acc.w += a1.y;
        acc2.x += b0.x; acc2.y += b0.y; acc2.z += b1.x; acc2.w += b1.y;
    }
    if (e < end) {
        uint2 u = xs2[(size_t)esrc[e] * 16 + c];
        float2 f0 = __half22float2(*(__half2*)&u.x), f1 = __half22float2(*(__half2*)&u.y);
        acc.x += f0.x; acc.y += f0.y; acc.z += f1.x; acc.w += f1.y;
    }
    acc.x += acc2.x; acc.y += acc2.y; acc.z += acc2.z; acc.w += acc2.w;
    acc.x += __shfl_xor(acc.x, 16, 64); acc.y += __shfl_xor(acc.y, 16, 64);
    acc.z += __shfl_xor(acc.z, 16, 64); acc.w += __shfl_xor(acc.w, 16, 64);
    acc.x += __shfl_xor(acc.x, 32, 64); acc.y += __shfl_xor(acc.y, 32, 64);
    acc.z += __shfl_xor(acc.z, 32, 64); acc.w += __shfl_xor(acc.w, 32, 64);
    if (g == 0) {
        float d = dinv[n];
        float4 bb = ((const float4*)bias)[c];
        float4 o;
        o.x = acc.x * d + bb.x; o.y = acc.y * d + bb.y;
        o.z = acc.z * d + bb.z; o.w = acc.w * d + bb.w;
        ((float4*)out)[(size_t)n * 16 + c] = o;
    }
}

// ---------------- fused MLP (MFMA fp16): ts = (relu(A@W1+b1) @ W2) * dinv ----
// Block = 4 waves, 64 nodes. Wave w: 16 nodes, gemm1 tile 16x128 (K=64),
// LDS transpose (C-layout -> A-layout), gemm2 tile 16x64 (K=128).
// MFMA 16x16x32 f16 layouts: A[m=lane&15][k=q*8+j], B[k=q*8+j][n=lane&15],
// C/D[row=q*4+reg][col=lane&15]  (q = lane>>4).
__global__ __launch_bounds__(256) void fusedmlp_kernel(const __half* __restrict__ A,
        const __half* __restrict__ W1s, const __half* __restrict__ W2s,
        const float* __restrict__ b1, const float* __restrict__ dinv,
        __half* __restrict__ T, int N) {
    __shared__ __align__(16) __half h1t[4][16][136];   // per-wave 16x128 tile, padded rows
    int tid = threadIdx.x;
    int w = tid >> 6, lane = tid & 63;
    int n15 = lane & 15, q = lane >> 4;
    int base = blockIdx.x * 64 + w * 16;

    // gemm1: A-frags (node row = n15)
    int m = base + n15; if (m >= N) m = N - 1;          // clamp; stores guarded
    const uint4* Ar = (const uint4*)(A + (size_t)m * 64);
    uint4 ua0 = Ar[q];
    uint4 ua1 = Ar[4 + q];
    f16x8 a10 = *(f16x8*)&ua0;
    f16x8 a11 = *(f16x8*)&ua1;
    const uint4* W1f = (const uint4*)W1s;
    #pragma unroll
    for (int nt = 0; nt < 8; ++nt) {
        f32x4 c = {0.f, 0.f, 0.f, 0.f};
        uint4 ub0 = W1f[(nt * 4 + q) * 16 + n15];           // ks=0
        uint4 ub1 = W1f[((8 + nt) * 4 + q) * 16 + n15];     // ks=1
        c = __builtin_amdgcn_mfma_f32_16x16x32_f16(a10, *(f16x8*)&ub0, c, 0, 0, 0);
        c = __builtin_amdgcn_mfma_f32_16x16x32_f16(a11, *(f16x8*)&ub1, c, 0, 0, 0);
        float bv = b1[nt * 16 + n15];
        #pragma unroll
        for (int rr = 0; rr < 4; ++rr) {
            float hv = fmaxf(c[rr] + bv, 0.f);
            h1t[w][q * 4 + rr][nt * 16 + n15] = (__half)hv;  // row=node, col=feat
        }
    }
    __syncthreads();

    // gemm2: A-frags from LDS (node row = n15, k strided)
    f16x8 a2[4];
    #pragma unroll
    for (int ks2 = 0; ks2 < 4; ++ks2)
        a2[ks2] = *(f16x8*)&h1t[w][n15][ks2 * 32 + q * 8];
    const uint4* W2f = (const uint4*)W2s;
    #pragma unroll
    for (int n2 = 0; n2 < 4; ++n2) {
        f32x4 c = {0.f, 0.f, 0.f, 0.f};
        #pragma unroll
        for (int ks2 = 0; ks2 < 4; ++ks2) {
            uint4 ub = W2f[((ks2 * 4 + n2) * 4 + q) * 16 + n15];
            c = __builtin_amdgcn_mfma_f32_16x16x32_f16(a2[ks2], *(f16x8*)&ub, c, 0, 0, 0);
        }
        #pragma unroll
        for (int rr = 0; rr < 4; ++rr) {
            int node = base + q * 4 + rr;
            if (node < N) {
                float v = c[rr] * dinv[node];
                T[(size_t)node * 64 + n2 * 16 + n15] = (__half)v;
            }
        }
    }
}

// ---------------- readout: r[g] = [mean(h2 rows), max(h2 rows)]  (batch sorted)
__global__ __launch_bounds__(256) void readout_kernel(const float* __restrict__ h2,
        const int* __restrict__ goff, float* __restrict__ r) {
    int g = blockIdx.x;
    int beg = goff[g], end = goff[g + 1];
    int f = threadIdx.x & 63;
    int c = threadIdx.x >> 6;
    float s = 0.f, m = -3.4e38f;
    for (int n = beg + c; n < end; n += 4) {
        float v = h2[(size_t)n * 64 + f];
        s += v;
        m = fmaxf(m, v);
    }
    __shared__ float ss[4][64], sm[4][64];
    ss[c][f] = s; sm[c][f] = m;
    __syncthreads();
    if (c == 0) {
        float S = ss[0][f] + ss[1][f] + ss[2][f] + ss[3][f];
        float M = fmaxf(fmaxf(sm[0][f], sm[1][f]), fmaxf(sm[2][f], sm[3][f]));
        int cnt = end - beg;
        float mean = (cnt > 0) ? S / (float)cnt : 0.f;
        if (cnt == 0) M = 0.f;
        r[(size_t)g * 128 + f] = mean;
        r[(size_t)g * 128 + 64 + f] = M;
    }
}

// ---------------- head: out[g] = r[g] @ Wm + bm   (1024 x 128 @ 128 x 64)
__global__ __launch_bounds__(64) void head_kernel(const float* __restrict__ r,
        const float* __restrict__ Wm, const float* __restrict__ bm,
        float* __restrict__ out) {
    int g = blockIdx.x;
    int j = threadIdx.x;
    float acc = bm[j];
    #pragma unroll 4
    for (int k = 0; k < 128; ++k)
        acc = fmaf(r[(size_t)g * 128 + k], Wm[k * 64 + j], acc);
    out[(size_t)g * 64 + j] = acc;
}

extern "C" void kernel_launch(void* const* d_in, const int* in_sizes, int n_in,
                              void* d_out, int out_size, void* d_ws, size_t ws_size,
                              hipStream_t stream) {
    const float* x    = (const float*)d_in[0];
    const int*  adj   = (const int*)d_in[1];
    const int*  batch = (const int*)d_in[2];
    const float* W1   = (const float*)d_in[3];
    const float* b1   = (const float*)d_in[4];
    const float* W2   = (const float*)d_in[5];
    const float* b2   = (const float*)d_in[6];
    const float* Wm   = (const float*)d_in[7];
    const float* bm   = (const float*)d_in[8];
    float* out = (float*)d_out;

    const int N = in_sizes[0] / 64;
    const int E = in_sizes[1] / 2;
    const int* src = adj;
    const int* dst = adj + E;
    const int B = (N + 255) >> 8;                 // buckets (391)
    const int nblocks = (E + CHUNK - 1) / CHUNK;  // coarse blocks (196)

    // ---- workspace carve (256B aligned) ----
    char* w = (char*)d_ws;
    size_t off = 0;
    auto carve = [&](size_t bytes) -> void* {
        void* p = w + off;
        off += (bytes + 255) & ~(size_t)255;
        return p;
    };
    size_t halfbuf = (size_t)N * 64 * 2;
    size_t ebbytes = (size_t)E * 4;
    size_t cntbytes = (size_t)MAXB * 256 * 4;
    float* dinv    = (float*)carve((size_t)N * 4);
    int*   row_off = (int*)  carve((size_t)(N + 1) * 4);
    int*   esrc    = (int*)  carve((size_t)E * 4);
    int*   btot    = (int*)  carve((MAXB + 1) * 4);
    int*   bbase   = (int*)  carve((MAXB + 1) * 4);
    int*   gcnt    = (int*)  carve(NGRAPH * 4);
    int*   goff    = (int*)  carve((NGRAPH + 1) * 4);
    __half* W1s    = (__half*)carve(8192 * 2);
    __half* W2s    = (__half*)carve(8192 * 2);
    __half* xs_h   = (__half*)carve(halfbuf > ebbytes ? halfbuf : ebbytes); // ebuck pre-pack; ts_h later
    __half* agg1h  = (__half*)carve(halfbuf > cntbytes ? halfbuf : cntbytes); // cnt pre-agg
    float* h2      = (float*)carve((size_t)N * 64 * 4);
    float* r       = (float*)carve((size_t)NGRAPH * 128 * 4);
    unsigned* ebuck = (unsigned*)xs_h; // dead before pack_kernel writes xs_h
    int*      cnt   = (int*)agg1h;     // dead before agg writes agg1h
    __half* ts_h = xs_h;               // xs_h dead after first agg

    hipMemsetAsync(btot, 0, (MAXB + 1) * 4, stream);
    hipMemsetAsync(gcnt, 0, NGRAPH * 4, stream);

    // weight pre-swizzle (independent)
    wconv_kernel<<<1, 256, 0, stream>>>(W1, W2, W1s, W2s);

    // CSR build (two-level bucket sort) + graph segment offsets
    coarse_hist_kernel<<<nblocks, 256, 0, stream>>>(dst, E, nblocks, B, cnt, btot);
    batch_count_kernel<<<(N + 255) / 256, 256, 0, stream>>>(batch, N, gcnt);
    bucket_scan_kernel<<<1, MAXB, 0, stream>>>(btot, bbase, B, E);
    offset_scan_kernel<<<B, 256, 0, stream>>>(cnt, bbase, nblocks);
    coarse_scatter_kernel<<<nblocks, 256, 0, stream>>>(src, dst, E, nblocks, B, cnt, ebuck);
    fine_kernel<<<B, 256, 0, stream>>>(ebuck, bbase, N, E, B, row_off, dinv, esrc);
    gscan_kernel<<<1, 1024, 0, stream>>>(gcnt, goff, N);

    // conv1: xs_h = half(x*dinv) ; agg1h = half(dinv*(S+I)xs)
    pack_kernel<<<(N * 16 + 255) / 256, 256, 0, stream>>>(x, dinv, xs_h, N * 16);
    agg_h2h_kernel<<<(N + 3) / 4, 256, 0, stream>>>(xs_h, esrc, row_off, dinv, agg1h, N);

    // fused MLP: ts_h = half((relu(agg1h@W1 + b1) @ W2) * dinv)
    fusedmlp_kernel<<<(N + 63) / 64, 256, 0, stream>>>(agg1h, W1s, W2s, b1, dinv, ts_h, N);

    // conv2 aggregate: h2 = dinv*(S+I)ts + b2
    agg_h2f_kernel<<<(N + 3) / 4, 256, 0, stream>>>(ts_h, esrc, row_off, dinv, b2, h2, N);

    // readout + head
    readout_kernel<<<NGRAPH, 256, 0, stream>>>(h2, goff, r);
    head_kernel<<<NGRAPH, 64, 0, stream>>>(r, Wm, bm, out);
}

// Round 6
// 384.045 us; speedup vs baseline: 2.2846x; 1.0787x over previous
//
#include <hip/hip_runtime.h>
#include <hip/hip_fp16.h>
#include <cstdint>
#include <cstddef>

// Problem constants (from reference): N=100000, F_IN=64, F1=128, F2=64,
// E=3200000, NUM_GRAPHS=1024. N and E derived from in_sizes at launch.
#define NGRAPH 1024
#define CHUNK 16384      // edges per block in coarse pass
#define MAXB 512         // max buckets (supports N <= 131072; here B=391)

typedef _Float16 f16x8 __attribute__((ext_vector_type(8)));
typedef float f32x4 __attribute__((ext_vector_type(4)));

// ================= two-level bucket CSR build =================
// bucket b = dst >> 8. Edge word packs (dst & 255) << 24 | src (src < 2^24).

__global__ __launch_bounds__(256) void coarse_hist_kernel(const int* __restrict__ dst,
        int E, int nblocks, int B, int* __restrict__ cnt, int* __restrict__ btot) {
    __shared__ int h[MAXB];
    int blk = blockIdx.x, tid = threadIdx.x;
    for (int i = tid; i < B; i += 256) h[i] = 0;
    __syncthreads();
    int base = blk * CHUNK;
    #pragma unroll 4
    for (int it = 0; it < CHUNK / 256; ++it) {
        int i = base + tid + it * 256;
        if (i < E) atomicAdd(&h[dst[i] >> 8], 1);
    }
    __syncthreads();
    for (int b = tid; b < B; b += 256) {
        int c = h[b];
        cnt[b * nblocks + blk] = c;
        if (c) atomicAdd(&btot[b], c);
    }
}

__global__ void bucket_scan_kernel(const int* __restrict__ btot, int* __restrict__ bbase,
                                   int B, int E) {
    __shared__ int sh[MAXB];
    int tid = threadIdx.x;
    int v = (tid < B) ? btot[tid] : 0;
    sh[tid] = v; __syncthreads();
    for (int o = 1; o < MAXB; o <<= 1) {
        int t = (tid >= o) ? sh[tid - o] : 0;
        __syncthreads();
        sh[tid] += t;
        __syncthreads();
    }
    if (tid < B) bbase[tid] = sh[tid] - v;
    if (tid == 0) bbase[B] = E;
}

__global__ __launch_bounds__(256) void offset_scan_kernel(int* __restrict__ cnt,
        const int* __restrict__ bbase, int nblocks) {
    __shared__ int sh[256];
    int b = blockIdx.x, tid = threadIdx.x;
    int v = (tid < nblocks) ? cnt[b * nblocks + tid] : 0;
    sh[tid] = v; __syncthreads();
    for (int o = 1; o < 256; o <<= 1) {
        int t = (tid >= o) ? sh[tid - o] : 0;
        __syncthreads();
        sh[tid] += t;
        __syncthreads();
    }
    if (tid < nblocks) cnt[b * nblocks + tid] = sh[tid] - v + bbase[b];
}

__global__ __launch_bounds__(256) void coarse_scatter_kernel(const int* __restrict__ src,
        const int* __restrict__ dst, int E, int nblocks, int B,
        const int* __restrict__ cnt, unsigned* __restrict__ ebuck) {
    __shared__ int loff[MAXB];
    int blk = blockIdx.x, tid = threadIdx.x;
    for (int b = tid; b < B; b += 256) loff[b] = cnt[b * nblocks + blk];
    __syncthreads();
    int base = blk * CHUNK;
    #pragma unroll 4
    for (int it = 0; it < CHUNK / 256; ++it) {
        int i = base + tid + it * 256;
        if (i < E) {
            int d = dst[i], s = src[i];
            int p = atomicAdd(&loff[d >> 8], 1);
            ebuck[p] = ((unsigned)(d & 255) << 24) | (unsigned)s;
        }
    }
}

// Pass D (+fused pack): one block per bucket. LDS histogram -> deg/dinv/row_off,
// LDS-cursor scatter of src into esrc, AND xs_h[n][f] = half(x[n][f]*dinv[n])
// for the bucket's 256 nodes (coalesced read of x, dinv from LDS).
__global__ __launch_bounds__(256) void fine_kernel(const unsigned* __restrict__ ebuck,
        const int* __restrict__ bbase, const float* __restrict__ x, int N, int E, int B,
        int* __restrict__ row_off, float* __restrict__ dinv, int* __restrict__ esrc,
        __half* __restrict__ xs) {
    __shared__ int hcnt[256];
    __shared__ int sc[256];
    __shared__ int loff[256];
    __shared__ float sdinv[256];
    int b = blockIdx.x, tid = threadIdx.x;
    int beg = bbase[b], end = bbase[b + 1];
    hcnt[tid] = 0;
    __syncthreads();
    for (int e = beg + tid; e < end; e += 256)
        atomicAdd(&hcnt[ebuck[e] >> 24], 1);
    __syncthreads();
    int v = hcnt[tid];
    sc[tid] = v; __syncthreads();
    for (int o = 1; o < 256; o <<= 1) {
        int t = (tid >= o) ? sc[tid - o] : 0;
        __syncthreads();
        sc[tid] += t;
        __syncthreads();
    }
    int excl = sc[tid] - v;
    int n = (b << 8) + tid;
    float d = rsqrtf((float)(v + 1));   // +1 self loop
    if (n < N) {
        row_off[n] = beg + excl;
        dinv[n] = d;
    }
    if (b == B - 1 && tid == 0) row_off[N] = E;
    loff[tid] = excl;
    sdinv[tid] = d;
    __syncthreads();
    for (int e = beg + tid; e < end; e += 256) {
        unsigned u = ebuck[e];
        int p = atomicAdd(&loff[u >> 24], 1);
        esrc[beg + p] = (int)(u & 0xFFFFFF);
    }
    // fused pack for this bucket's nodes
    const float4* xr = (const float4*)x;
    #pragma unroll
    for (int it = 0; it < 16; ++it) {
        int j = tid + it * 256;               // 0..4095
        int node = j >> 4, cc = j & 15;
        int gn = (b << 8) + node;
        if (gn < N) {
            float dd = sdinv[node];
            float4 vv = xr[(size_t)gn * 16 + cc];
            __half2 h0 = __floats2half2_rn(vv.x * dd, vv.y * dd);
            __half2 h1 = __floats2half2_rn(vv.z * dd, vv.w * dd);
            uint2 u;
            u.x = *(unsigned*)&h0;
            u.y = *(unsigned*)&h1;
            ((uint2*)xs)[(size_t)gn * 16 + cc] = u;
        }
    }
}

// ================= batch (readout segment) preprocessing =================

__global__ void batch_count_kernel(const int* __restrict__ batch, int N, int* __restrict__ gcnt) {
    int i = blockIdx.x * blockDim.x + threadIdx.x;
    if (i < N) atomicAdd(&gcnt[batch[i]], 1);
}

__global__ void gscan_kernel(const int* __restrict__ gcnt, int* __restrict__ goff, int N) {
    __shared__ int sh[1024];
    int tid = threadIdx.x;
    int v = gcnt[tid];
    sh[tid] = v; __syncthreads();
    for (int o = 1; o < 1024; o <<= 1) {
        int t = (tid >= o) ? sh[tid - o] : 0;
        __syncthreads();
        sh[tid] += t;
        __syncthreads();
    }
    goff[tid] = sh[tid] - v;
    if (tid == 1023) goff[1024] = N;
}

// ---------------- weight pre-swizzle: frag-linear fp16 layouts ----------------
__global__ __launch_bounds__(256) void wconv_kernel(const float* __restrict__ W1,
        const float* __restrict__ W2, __half* __restrict__ W1s, __half* __restrict__ W2s) {
    int t = threadIdx.x;
    #pragma unroll
    for (int it = 0; it < 4; ++it) {
        int s = t + it * 256;
        int n = s & 15, q = (s >> 4) & 3, nt = (s >> 6) & 7, ks = s >> 9;
        int k0 = ks * 32 + q * 8, col = nt * 16 + n;
        __align__(16) __half h[8];
        #pragma unroll
        for (int j = 0; j < 8; ++j) h[j] = (__half)W1[(k0 + j) * 128 + col];
        *((uint4*)&W1s[(size_t)s * 8]) = *(uint4*)h;
    }
    #pragma unroll
    for (int it = 0; it < 4; ++it) {
        int s = t + it * 256;
        int n = s & 15, q = (s >> 4) & 3, n2 = (s >> 6) & 3, ks2 = s >> 8;
        int k0 = ks2 * 32 + q * 8, col = n2 * 16 + n;
        __align__(16) __half h[8];
        #pragma unroll
        for (int j = 0; j < 8; ++j) h[j] = (__half)W2[(k0 + j) * 64 + col];
        *((uint4*)&W2s[(size_t)s * 8]) = *(uint4*)h;
    }
}

// ---------------- aggregation (fp16 gather, fp32 accumulate) ----------------
// 64-lane wave per node: 8 groups x 8 lanes; group g gathers edge slot g,
// lane chunk c covers features c*8..c*8+7 (uint4 = 8 halfs). 2-deep unroll.
// Cross-group reduce: shfl_xor 8,16,32.
__device__ inline void acc8(float* a, const uint4& u) {
    const __half2* h = (const __half2*)&u;
    #pragma unroll
    for (int i = 0; i < 4; ++i) {
        float2 f = __half22float2(h[i]);
        a[2 * i]     += f.x;
        a[2 * i + 1] += f.y;
    }
}

// Variant 1: fp16 output, no bias (conv1 -> feeds MFMA GEMM)
__global__ __launch_bounds__(256) void agg_h2h_kernel(const __half* __restrict__ xs,
        const int* __restrict__ esrc, const int* __restrict__ row_off,
        const float* __restrict__ dinv, __half* __restrict__ out, int N) {
    int n = blockIdx.x * 4 + (threadIdx.x >> 6);
    if (n >= N) return;
    int lane = threadIdx.x & 63;
    int g = lane >> 3, c = lane & 7;
    const uint4* xs4 = (const uint4*)xs;     // row stride 8 uint4
    int beg = row_off[n], end = row_off[n + 1];
    float a[8] = {}, bacc[8] = {};
    if (g == 0) acc8(a, xs4[(size_t)n * 8 + c]);   // self loop
    int e = beg + g;
    for (; e + 8 < end; e += 16) {
        int s0 = esrc[e], s1 = esrc[e + 8];
        uint4 u0 = xs4[(size_t)s0 * 8 + c];
        uint4 u1 = xs4[(size_t)s1 * 8 + c];
        acc8(a, u0);
        acc8(bacc, u1);
    }
    if (e < end) acc8(a, xs4[(size_t)esrc[e] * 8 + c]);
    #pragma unroll
    for (int i = 0; i < 8; ++i) a[i] += bacc[i];
    #pragma unroll
    for (int i = 0; i < 8; ++i) {
        a[i] += __shfl_xor(a[i], 8, 64);
        a[i] += __shfl_xor(a[i], 16, 64);
        a[i] += __shfl_xor(a[i], 32, 64);
    }
    if (g == 0) {
        float d = dinv[n];
        __align__(16) __half2 h[4];
        #pragma unroll
        for (int i = 0; i < 4; ++i)
            h[i] = __floats2half2_rn(a[2 * i] * d, a[2 * i + 1] * d);
        ((uint4*)out)[(size_t)n * 8 + c] = *(uint4*)h;
    }
}

// Variant 2: fp32 output + bias (conv2 -> feeds readout)
__global__ __launch_bounds__(256) void agg_h2f_kernel(const __half* __restrict__ xs,
        const int* __restrict__ esrc, const int* __restrict__ row_off,
        const float* __restrict__ dinv, const float* __restrict__ bias,
        float* __restrict__ out, int N) {
    int n = blockIdx.x * 4 + (threadIdx.x >> 6);
    if (n >= N) return;
    int lane = threadIdx.x & 63;
    int g = lane >> 3, c = lane & 7;
    const uint4* xs4 = (const uint4*)xs;
    int beg = row_off[n], end = row_off[n + 1];
    float a[8] = {}, bacc[8] = {};
    if (g == 0) acc8(a, xs4[(size_t)n * 8 + c]);
    int e = beg + g;
    for (; e + 8 < end; e += 16) {
        int s0 = esrc[e], s1 = esrc[e + 8];
        uint4 u0 = xs4[(size_t)s0 * 8 + c];
        uint4 u1 = xs4[(size_t)s1 * 8 + c];
        acc8(a, u0);
        acc8(bacc, u1);
    }
    if (e < end) acc8(a, xs4[(size_t)esrc[e] * 8 + c]);
    #pragma unroll
    for (int i = 0; i < 8; ++i) a[i] += bacc[i];
    #pragma unroll
    for (int i = 0; i < 8; ++i) {
        a[i] += __shfl_xor(a[i], 8, 64);
        a[i] += __shfl_xor(a[i], 16, 64);
        a[i] += __shfl_xor(a[i], 32, 64);
    }
    if (g == 0) {
        float d = dinv[n];
        float4 bb0 = ((const float4*)bias)[c * 2];
        float4 bb1 = ((const float4*)bias)[c * 2 + 1];
        float4 o0, o1;
        o0.x = a[0] * d + bb0.x; o0.y = a[1] * d + bb0.y;
        o0.z = a[2] * d + bb0.z; o0.w = a[3] * d + bb0.w;
        o1.x = a[4] * d + bb1.x; o1.y = a[5] * d + bb1.y;
        o1.z = a[6] * d + bb1.z; o1.w = a[7] * d + bb1.w;
        ((float4*)out)[(size_t)n * 16 + c * 2] = o0;
        ((float4*)out)[(size_t)n * 16 + c * 2 + 1] = o1;
    }
}

// ---------------- fused MLP (MFMA fp16): ts = (relu(A@W1+b1) @ W2) * dinv ----
__global__ __launch_bounds__(256) void fusedmlp_kernel(const __half* __restrict__ A,
        const __half* __restrict__ W1s, const __half* __restrict__ W2s,
        const float* __restrict__ b1, const float* __restrict__ dinv,
        __half* __restrict__ T, int N) {
    __shared__ __align__(16) __half h1t[4][16][136];   // per-wave 16x128 tile, padded rows
    int tid = threadIdx.x;
    int w = tid >> 6, lane = tid & 63;
    int n15 = lane & 15, q = lane >> 4;
    int base = blockIdx.x * 64 + w * 16;

    int m = base + n15; if (m >= N) m = N - 1;          // clamp; stores guarded
    const uint4* Ar = (const uint4*)(A + (size_t)m * 64);
    uint4 ua0 = Ar[q];
    uint4 ua1 = Ar[4 + q];
    f16x8 a10 = *(f16x8*)&ua0;
    f16x8 a11 = *(f16x8*)&ua1;
    const uint4* W1f = (const uint4*)W1s;
    #pragma unroll
    for (int nt = 0; nt < 8; ++nt) {
        f32x4 c = {0.f, 0.f, 0.f, 0.f};
        uint4 ub0 = W1f[(nt * 4 + q) * 16 + n15];           // ks=0
        uint4 ub1 = W1f[((8 + nt) * 4 + q) * 16 + n15];     // ks=1
        c = __builtin_amdgcn_mfma_f32_16x16x32_f16(a10, *(f16x8*)&ub0, c, 0, 0, 0);
        c = __builtin_amdgcn_mfma_f32_16x16x32_f16(a11, *(f16x8*)&ub1, c, 0, 0, 0);
        float bv = b1[nt * 16 + n15];
        #pragma unroll
        for (int rr = 0; rr < 4; ++rr) {
            float hv = fmaxf(c[rr] + bv, 0.f);
            h1t[w][q * 4 + rr][nt * 16 + n15] = (__half)hv;  // row=node, col=feat
        }
    }
    __syncthreads();

    f16x8 a2[4];
    #pragma unroll
    for (int ks2 = 0; ks2 < 4; ++ks2)
        a2[ks2] = *(f16x8*)&h1t[w][n15][ks2 * 32 + q * 8];
    const uint4* W2f = (const uint4*)W2s;
    #pragma unroll
    for (int n2 = 0; n2 < 4; ++n2) {
        f32x4 c = {0.f, 0.f, 0.f, 0.f};
        #pragma unroll
        for (int ks2 = 0; ks2 < 4; ++ks2) {
            uint4 ub = W2f[((ks2 * 4 + n2) * 4 + q) * 16 + n15];
            c = __builtin_amdgcn_mfma_f32_16x16x32_f16(a2[ks2], *(f16x8*)&ub, c, 0, 0, 0);
        }
        #pragma unroll
        for (int rr = 0; rr < 4; ++rr) {
            int node = base + q * 4 + rr;
            if (node < N) {
                float v = c[rr] * dinv[node];
                T[(size_t)node * 64 + n2 * 16 + n15] = (__half)v;
            }
        }
    }
}

// ---------------- fused readout + head: out[g] = [mean|max](h2 rows) @ Wm + bm
__global__ __launch_bounds__(256) void readout_head_kernel(const float* __restrict__ h2,
        const int* __restrict__ goff, const float* __restrict__ Wm,
        const float* __restrict__ bm, float* __restrict__ out) {
    int g = blockIdx.x;
    int beg = goff[g], end = goff[g + 1];
    int f = threadIdx.x & 63;
    int c = threadIdx.x >> 6;
    float s = 0.f, m = -3.4e38f;
    for (int n = beg + c; n < end; n += 4) {
        float v = h2[(size_t)n * 64 + f];
        s += v;
        m = fmaxf(m, v);
    }
    __shared__ float ss[4][64], sm[4][64];
    __shared__ float rr[128];
    ss[c][f] = s; sm[c][f] = m;
    __syncthreads();
    if (c == 0) {
        float S = ss[0][f] + ss[1][f] + ss[2][f] + ss[3][f];
        float M = fmaxf(fmaxf(sm[0][f], sm[1][f]), fmaxf(sm[2][f], sm[3][f]));
        int cnt = end - beg;
        rr[f] = (cnt > 0) ? S / (float)cnt : 0.f;
        rr[64 + f] = (cnt > 0) ? M : 0.f;
    }
    __syncthreads();
    if (threadIdx.x < 64) {
        int j = threadIdx.x;
        float acc = bm[j];
        #pragma unroll 4
        for (int k = 0; k < 128; ++k)
            acc = fmaf(rr[k], Wm[k * 64 + j], acc);
        out[(size_t)g * 64 + j] = acc;
    }
}

extern "C" void kernel_launch(void* const* d_in, const int* in_sizes, int n_in,
                              void* d_out, int out_size, void* d_ws, size_t ws_size,
                              hipStream_t stream) {
    const float* x    = (const float*)d_in[0];
    const int*  adj   = (const int*)d_in[1];
    const int*  batch = (const int*)d_in[2];
    const float* W1   = (const float*)d_in[3];
    const float* b1   = (const float*)d_in[4];
    const float* W2   = (const float*)d_in[5];
    const float* b2   = (const float*)d_in[6];
    const float* Wm   = (const float*)d_in[7];
    const float* bm   = (const float*)d_in[8];
    float* out = (float*)d_out;

    const int N = in_sizes[0] / 64;
    const int E = in_sizes[1] / 2;
    const int* src = adj;
    const int* dst = adj + E;
    const int B = (N + 255) >> 8;                 // buckets (391)
    const int nblocks = (E + CHUNK - 1) / CHUNK;  // coarse blocks (196)

    // ---- workspace carve (256B aligned) ----
    char* w = (char*)d_ws;
    size_t off = 0;
    auto carve = [&](size_t bytes) -> void* {
        void* p = w + off;
        off += (bytes + 255) & ~(size_t)255;
        return p;
    };
    size_t halfbuf = (size_t)N * 64 * 2;
    size_t cntbytes = (size_t)MAXB * 256 * 4;
    float* dinv    = (float*)carve((size_t)N * 4);
    int*   row_off = (int*)  carve((size_t)(N + 1) * 4);
    int*   esrc    = (int*)  carve((size_t)E * 4);
    unsigned* ebuck= (unsigned*)carve((size_t)E * 4);
    int*   btot    = (int*)  carve((MAXB + 1) * 4);
    int*   bbase   = (int*)  carve((MAXB + 1) * 4);
    int*   gcnt    = (int*)  carve(NGRAPH * 4);
    int*   goff    = (int*)  carve((NGRAPH + 1) * 4);
    __half* W1s    = (__half*)carve(8192 * 2);
    __half* W2s    = (__half*)carve(8192 * 2);
    __half* xs_h   = (__half*)carve(halfbuf);             // later reused as ts_h
    __half* agg1h  = (__half*)carve(halfbuf > cntbytes ? halfbuf : cntbytes); // cnt pre-agg
    float* h2      = (float*)carve((size_t)N * 64 * 4);
    int*      cnt   = (int*)agg1h;     // dead before agg writes agg1h
    __half* ts_h = xs_h;               // xs_h dead after first agg

    hipMemsetAsync(btot, 0, (MAXB + 1) * 4, stream);
    hipMemsetAsync(gcnt, 0, NGRAPH * 4, stream);

    // weight pre-swizzle (independent)
    wconv_kernel<<<1, 256, 0, stream>>>(W1, W2, W1s, W2s);

    // CSR build (two-level bucket sort) + fused x pre-scale + graph offsets
    coarse_hist_kernel<<<nblocks, 256, 0, stream>>>(dst, E, nblocks, B, cnt, btot);
    batch_count_kernel<<<(N + 255) / 256, 256, 0, stream>>>(batch, N, gcnt);
    bucket_scan_kernel<<<1, MAXB, 0, stream>>>(btot, bbase, B, E);
    offset_scan_kernel<<<B, 256, 0, stream>>>(cnt, bbase, nblocks);
    coarse_scatter_kernel<<<nblocks, 256, 0, stream>>>(src, dst, E, nblocks, B, cnt, ebuck);
    fine_kernel<<<B, 256, 0, stream>>>(ebuck, bbase, x, N, E, B, row_off, dinv, esrc, xs_h);
    gscan_kernel<<<1, 1024, 0, stream>>>(gcnt, goff, N);

    // conv1 aggregate: agg1h = half(dinv*(S+I)xs)
    agg_h2h_kernel<<<(N + 3) / 4, 256, 0, stream>>>(xs_h, esrc, row_off, dinv, agg1h, N);

    // fused MLP: ts_h = half((relu(agg1h@W1 + b1) @ W2) * dinv)
    fusedmlp_kernel<<<(N + 63) / 64, 256, 0, stream>>>(agg1h, W1s, W2s, b1, dinv, ts_h, N);

    // conv2 aggregate: h2 = dinv*(S+I)ts + b2
    agg_h2f_kernel<<<(N + 3) / 4, 256, 0, stream>>>(ts_h, esrc, row_off, dinv, b2, h2, N);

    // fused readout + head
    readout_head_kernel<<<NGRAPH, 256, 0, stream>>>(h2, goff, Wm, bm, out);
}

// Round 7
// 346.040 us; speedup vs baseline: 2.5355x; 1.1098x over previous
//
#include <hip/hip_runtime.h>
#include <hip/hip_fp16.h>
#include <cstdint>
#include <cstddef>

// Problem constants (from reference): N=100000, F_IN=64, F1=128, F2=64,
// E=3200000, NUM_GRAPHS=1024. N and E derived from in_sizes at launch.
#define NGRAPH 1024
#define CHUNK 16384      // edges per block in coarse pass
#define MAXB 512         // max buckets (supports N <= 131072; here B=391)

typedef _Float16 f16x8 __attribute__((ext_vector_type(8)));
typedef float f32x4 __attribute__((ext_vector_type(4)));

// ================= two-level bucket CSR build =================
// bucket b = dst >> 8. Edge word packs (dst & 255) << 24 | src (src < 2^24).

__global__ __launch_bounds__(256) void coarse_hist_kernel(const int* __restrict__ dst,
        int E, int nblocks, int B, int* __restrict__ cnt, int* __restrict__ btot) {
    __shared__ int h[MAXB];
    int blk = blockIdx.x, tid = threadIdx.x;
    for (int i = tid; i < B; i += 256) h[i] = 0;
    __syncthreads();
    int base = blk * CHUNK;
    #pragma unroll 4
    for (int it = 0; it < CHUNK / 256; ++it) {
        int i = base + tid + it * 256;
        if (i < E) atomicAdd(&h[dst[i] >> 8], 1);
    }
    __syncthreads();
    for (int b = tid; b < B; b += 256) {
        int c = h[b];
        cnt[b * nblocks + blk] = c;
        if (c) atomicAdd(&btot[b], c);
    }
}

// Per-bucket: bbase[b] = sum btot[0..b) (local reduce), then cross-block scan
// of cnt[b][*] offset by bbase[b] (in place). Also writes bbase[] for fine.
__global__ __launch_bounds__(256) void offset_scan_kernel(int* __restrict__ cnt,
        const int* __restrict__ btot, int* __restrict__ bbase,
        int nblocks, int B, int E) {
    __shared__ int red[256];
    __shared__ int sh[256];
    int b = blockIdx.x, tid = threadIdx.x;
    int partial = 0;
    for (int j = tid; j < b; j += 256) partial += btot[j];
    red[tid] = partial; __syncthreads();
    for (int o = 128; o > 0; o >>= 1) {
        if (tid < o) red[tid] += red[tid + o];
        __syncthreads();
    }
    int base = red[0];
    if (tid == 0) {
        bbase[b] = base;
        if (b == B - 1) bbase[B] = E;
    }
    int v = (tid < nblocks) ? cnt[b * nblocks + tid] : 0;
    sh[tid] = v; __syncthreads();
    for (int o = 1; o < 256; o <<= 1) {
        int t = (tid >= o) ? sh[tid - o] : 0;
        __syncthreads();
        sh[tid] += t;
        __syncthreads();
    }
    if (tid < nblocks) cnt[b * nblocks + tid] = sh[tid] - v + base;
}

__global__ __launch_bounds__(256) void coarse_scatter_kernel(const int* __restrict__ src,
        const int* __restrict__ dst, int E, int nblocks, int B,
        const int* __restrict__ cnt, unsigned* __restrict__ ebuck) {
    __shared__ int loff[MAXB];
    int blk = blockIdx.x, tid = threadIdx.x;
    for (int b = tid; b < B; b += 256) loff[b] = cnt[b * nblocks + blk];
    __syncthreads();
    int base = blk * CHUNK;
    #pragma unroll 4
    for (int it = 0; it < CHUNK / 256; ++it) {
        int i = base + tid + it * 256;
        if (i < E) {
            int d = dst[i], s = src[i];
            int p = atomicAdd(&loff[d >> 8], 1);
            ebuck[p] = ((unsigned)(d & 255) << 24) | (unsigned)s;
        }
    }
}

// Pass D (+fused pack): one block per bucket. LDS histogram -> deg/dinv/row_off,
// LDS-cursor scatter of src into esrc, AND xs_h[n][f] = half(x[n][f]*dinv[n])
// for the bucket's 256 nodes (coalesced read of x, dinv from LDS).
__global__ __launch_bounds__(256) void fine_kernel(const unsigned* __restrict__ ebuck,
        const int* __restrict__ bbase, const float* __restrict__ x, int N, int E, int B,
        int* __restrict__ row_off, float* __restrict__ dinv, int* __restrict__ esrc,
        __half* __restrict__ xs) {
    __shared__ int hcnt[256];
    __shared__ int sc[256];
    __shared__ int loff[256];
    __shared__ float sdinv[256];
    int b = blockIdx.x, tid = threadIdx.x;
    int beg = bbase[b], end = bbase[b + 1];
    hcnt[tid] = 0;
    __syncthreads();
    for (int e = beg + tid; e < end; e += 256)
        atomicAdd(&hcnt[ebuck[e] >> 24], 1);
    __syncthreads();
    int v = hcnt[tid];
    sc[tid] = v; __syncthreads();
    for (int o = 1; o < 256; o <<= 1) {
        int t = (tid >= o) ? sc[tid - o] : 0;
        __syncthreads();
        sc[tid] += t;
        __syncthreads();
    }
    int excl = sc[tid] - v;
    int n = (b << 8) + tid;
    float d = rsqrtf((float)(v + 1));   // +1 self loop
    if (n < N) {
        row_off[n] = beg + excl;
        dinv[n] = d;
    }
    if (b == B - 1 && tid == 0) row_off[N] = E;
    loff[tid] = excl;
    sdinv[tid] = d;
    __syncthreads();
    for (int e = beg + tid; e < end; e += 256) {
        unsigned u = ebuck[e];
        int p = atomicAdd(&loff[u >> 24], 1);
        esrc[beg + p] = (int)(u & 0xFFFFFF);
    }
    // fused pack for this bucket's nodes
    const float4* xr = (const float4*)x;
    #pragma unroll
    for (int it = 0; it < 16; ++it) {
        int j = tid + it * 256;               // 0..4095
        int node = j >> 4, cc = j & 15;
        int gn = (b << 8) + node;
        if (gn < N) {
            float dd = sdinv[node];
            float4 vv = xr[(size_t)gn * 16 + cc];
            __half2 h0 = __floats2half2_rn(vv.x * dd, vv.y * dd);
            __half2 h1 = __floats2half2_rn(vv.z * dd, vv.w * dd);
            uint2 u;
            u.x = *(unsigned*)&h0;
            u.y = *(unsigned*)&h1;
            ((uint2*)xs)[(size_t)gn * 16 + cc] = u;
        }
    }
}

// ================= batch (readout segment) offsets: binary search (batch sorted)
__global__ void goff_kernel(const int* __restrict__ batch, int N, int* __restrict__ goff) {
    int g = blockIdx.x * blockDim.x + threadIdx.x;
    if (g > NGRAPH) return;
    if (g == NGRAPH) { goff[g] = N; return; }
    int lo = 0, hi = N;
    while (lo < hi) {
        int mid = (lo + hi) >> 1;
        if (batch[mid] < g) lo = mid + 1; else hi = mid;
    }
    goff[g] = lo;
}

// ---------------- weight pre-swizzle: frag-linear fp16 layouts ----------------
__global__ __launch_bounds__(256) void wconv_kernel(const float* __restrict__ W1,
        const float* __restrict__ W2, __half* __restrict__ W1s, __half* __restrict__ W2s) {
    int t = threadIdx.x;
    #pragma unroll
    for (int it = 0; it < 4; ++it) {
        int s = t + it * 256;
        int n = s & 15, q = (s >> 4) & 3, nt = (s >> 6) & 7, ks = s >> 9;
        int k0 = ks * 32 + q * 8, col = nt * 16 + n;
        __align__(16) __half h[8];
        #pragma unroll
        for (int j = 0; j < 8; ++j) h[j] = (__half)W1[(k0 + j) * 128 + col];
        *((uint4*)&W1s[(size_t)s * 8]) = *(uint4*)h;
    }
    #pragma unroll
    for (int it = 0; it < 4; ++it) {
        int s = t + it * 256;
        int n = s & 15, q = (s >> 4) & 3, n2 = (s >> 6) & 3, ks2 = s >> 8;
        int k0 = ks2 * 32 + q * 8, col = n2 * 16 + n;
        __align__(16) __half h[8];
        #pragma unroll
        for (int j = 0; j < 8; ++j) h[j] = (__half)W2[(k0 + j) * 64 + col];
        *((uint4*)&W2s[(size_t)s * 8]) = *(uint4*)h;
    }
}

// ---------------- aggregation (fp16 gather, packed fp16 partial accumulate) ---
// 64-lane wave per node: 8 groups x 8 lanes; group g gathers edge slot g,
// lane chunk c covers features c*8..c*8+7 (uint4 = 8 halfs). 2-deep unroll.
// Each fp16 accumulator sums only ~deg/16 (~2-4) terms -> error ~1 ulp.
// Convert to fp32 after the loop; cross-group reduce via shfl_xor 8,16,32.
__device__ inline void acc8h(__half2* a, const uint4& u) {
    const __half2* h = (const __half2*)&u;
    #pragma unroll
    for (int i = 0; i < 4; ++i) a[i] = __hadd2(a[i], h[i]);
}

// Variant 1: fp16 output, no bias (conv1 -> feeds MFMA GEMM)
__global__ __launch_bounds__(256) void agg_h2h_kernel(const __half* __restrict__ xs,
        const int* __restrict__ esrc, const int* __restrict__ row_off,
        const float* __restrict__ dinv, __half* __restrict__ out, int N) {
    int n = blockIdx.x * 4 + (threadIdx.x >> 6);
    if (n >= N) return;
    int lane = threadIdx.x & 63;
    int g = lane >> 3, c = lane & 7;
    const uint4* xs4 = (const uint4*)xs;     // row stride 8 uint4
    int beg = row_off[n], end = row_off[n + 1];
    __half2 ha[4] = {}, hb[4] = {};
    if (g == 0) acc8h(ha, xs4[(size_t)n * 8 + c]);   // self loop
    int e = beg + g;
    for (; e + 8 < end; e += 16) {
        int s0 = esrc[e], s1 = esrc[e + 8];
        uint4 u0 = xs4[(size_t)s0 * 8 + c];
        uint4 u1 = xs4[(size_t)s1 * 8 + c];
        acc8h(ha, u0);
        acc8h(hb, u1);
    }
    if (e < end) acc8h(ha, xs4[(size_t)esrc[e] * 8 + c]);
    float a[8];
    #pragma unroll
    for (int i = 0; i < 4; ++i) {
        float2 fa = __half22float2(ha[i]), fb = __half22float2(hb[i]);
        a[2 * i]     = fa.x + fb.x;
        a[2 * i + 1] = fa.y + fb.y;
    }
    #pragma unroll
    for (int i = 0; i < 8; ++i) {
        a[i] += __shfl_xor(a[i], 8, 64);
        a[i] += __shfl_xor(a[i], 16, 64);
        a[i] += __shfl_xor(a[i], 32, 64);
    }
    if (g == 0) {
        float d = dinv[n];
        __align__(16) __half2 h[4];
        #pragma unroll
        for (int i = 0; i < 4; ++i)
            h[i] = __floats2half2_rn(a[2 * i] * d, a[2 * i + 1] * d);
        ((uint4*)out)[(size_t)n * 8 + c] = *(uint4*)h;
    }
}

// Variant 2: fp32 output + bias (conv2 -> feeds readout)
__global__ __launch_bounds__(256) void agg_h2f_kernel(const __half* __restrict__ xs,
        const int* __restrict__ esrc, const int* __restrict__ row_off,
        const float* __restrict__ dinv, const float* __restrict__ bias,
        float* __restrict__ out, int N) {
    int n = blockIdx.x * 4 + (threadIdx.x >> 6);
    if (n >= N) return;
    int lane = threadIdx.x & 63;
    int g = lane >> 3, c = lane & 7;
    const uint4* xs4 = (const uint4*)xs;
    int beg = row_off[n], end = row_off[n + 1];
    __half2 ha[4] = {}, hb[4] = {};
    if (g == 0) acc8h(ha, xs4[(size_t)n * 8 + c]);
    int e = beg + g;
    for (; e + 8 < end; e += 16) {
        int s0 = esrc[e], s1 = esrc[e + 8];
        uint4 u0 = xs4[(size_t)s0 * 8 + c];
        uint4 u1 = xs4[(size_t)s1 * 8 + c];
        acc8h(ha, u0);
        acc8h(hb, u1);
    }
    if (e < end) acc8h(ha, xs4[(size_t)esrc[e] * 8 + c]);
    float a[8];
    #pragma unroll
    for (int i = 0; i < 4; ++i) {
        float2 fa = __half22float2(ha[i]), fb = __half22float2(hb[i]);
        a[2 * i]     = fa.x + fb.x;
        a[2 * i + 1] = fa.y + fb.y;
    }
    #pragma unroll
    for (int i = 0; i < 8; ++i) {
        a[i] += __shfl_xor(a[i], 8, 64);
        a[i] += __shfl_xor(a[i], 16, 64);
        a[i] += __shfl_xor(a[i], 32, 64);
    }
    if (g == 0) {
        float d = dinv[n];
        float4 bb0 = ((const float4*)bias)[c * 2];
        float4 bb1 = ((const float4*)bias)[c * 2 + 1];
        float4 o0, o1;
        o0.x = a[0] * d + bb0.x; o0.y = a[1] * d + bb0.y;
        o0.z = a[2] * d + bb0.z; o0.w = a[3] * d + bb0.w;
        o1.x = a[4] * d + bb1.x; o1.y = a[5] * d + bb1.y;
        o1.z = a[6] * d + bb1.z; o1.w = a[7] * d + bb1.w;
        ((float4*)out)[(size_t)n * 16 + c * 2] = o0;
        ((float4*)out)[(size_t)n * 16 + c * 2 + 1] = o1;
    }
}

// ---------------- fused MLP (MFMA fp16): ts = (relu(A@W1+b1) @ W2) * dinv ----
__global__ __launch_bounds__(256) void fusedmlp_kernel(const __half* __restrict__ A,
        const __half* __restrict__ W1s, const __half* __restrict__ W2s,
        const float* __restrict__ b1, const float* __restrict__ dinv,
        __half* __restrict__ T, int N) {
    __shared__ __align__(16) __half h1t[4][16][136];   // per-wave 16x128 tile, padded rows
    int tid = threadIdx.x;
    int w = tid >> 6, lane = tid & 63;
    int n15 = lane & 15, q = lane >> 4;
    int base = blockIdx.x * 64 + w * 16;

    int m = base + n15; if (m >= N) m = N - 1;          // clamp; stores guarded
    const uint4* Ar = (const uint4*)(A + (size_t)m * 64);
    uint4 ua0 = Ar[q];
    uint4 ua1 = Ar[4 + q];
    f16x8 a10 = *(f16x8*)&ua0;
    f16x8 a11 = *(f16x8*)&ua1;
    const uint4* W1f = (const uint4*)W1s;
    #pragma unroll
    for (int nt = 0; nt < 8; ++nt) {
        f32x4 c = {0.f, 0.f, 0.f, 0.f};
        uint4 ub0 = W1f[(nt * 4 + q) * 16 + n15];           // ks=0
        uint4 ub1 = W1f[((8 + nt) * 4 + q) * 16 + n15];     // ks=1
        c = __builtin_amdgcn_mfma_f32_16x16x32_f16(a10, *(f16x8*)&ub0, c, 0, 0, 0);
        c = __builtin_amdgcn_mfma_f32_16x16x32_f16(a11, *(f16x8*)&ub1, c, 0, 0, 0);
        float bv = b1[nt * 16 + n15];
        #pragma unroll
        for (int rr = 0; rr < 4; ++rr) {
            float hv = fmaxf(c[rr] + bv, 0.f);
            h1t[w][q * 4 + rr][nt * 16 + n15] = (__half)hv;  // row=node, col=feat
        }
    }
    __syncthreads();

    f16x8 a2[4];
    #pragma unroll
    for (int ks2 = 0; ks2 < 4; ++ks2)
        a2[ks2] = *(f16x8*)&h1t[w][n15][ks2 * 32 + q * 8];
    const uint4* W2f = (const uint4*)W2s;
    #pragma unroll
    for (int n2 = 0; n2 < 4; ++n2) {
        f32x4 c = {0.f, 0.f, 0.f, 0.f};
        #pragma unroll
        for (int ks2 = 0; ks2 < 4; ++ks2) {
            uint4 ub = W2f[((ks2 * 4 + n2) * 4 + q) * 16 + n15];
            c = __builtin_amdgcn_mfma_f32_16x16x32_f16(a2[ks2], *(f16x8*)&ub, c, 0, 0, 0);
        }
        #pragma unroll
        for (int rr = 0; rr < 4; ++rr) {
            int node = base + q * 4 + rr;
            if (node < N) {
                float v = c[rr] * dinv[node];
                T[(size_t)node * 64 + n2 * 16 + n15] = (__half)v;
            }
        }
    }
}

// ---------------- fused readout + head: out[g] = [mean|max](h2 rows) @ Wm + bm
__global__ __launch_bounds__(256) void readout_head_kernel(const float* __restrict__ h2,
        const int* __restrict__ goff, const float* __restrict__ Wm,
        const float* __restrict__ bm, float* __restrict__ out) {
    int g = blockIdx.x;
    int beg = goff[g], end = goff[g + 1];
    int f = threadIdx.x & 63;
    int c = threadIdx.x >> 6;
    float s = 0.f, m = -3.4e38f;
    for (int n = beg + c; n < end; n += 4) {
        float v = h2[(size_t)n * 64 + f];
        s += v;
        m = fmaxf(m, v);
    }
    __shared__ float ss[4][64], sm[4][64];
    __shared__ float rr[128];
    ss[c][f] = s; sm[c][f] = m;
    __syncthreads();
    if (c == 0) {
        float S = ss[0][f] + ss[1][f] + ss[2][f] + ss[3][f];
        float M = fmaxf(fmaxf(sm[0][f], sm[1][f]), fmaxf(sm[2][f], sm[3][f]));
        int cnt = end - beg;
        rr[f] = (cnt > 0) ? S / (float)cnt : 0.f;
        rr[64 + f] = (cnt > 0) ? M : 0.f;
    }
    __syncthreads();
    if (threadIdx.x < 64) {
        int j = threadIdx.x;
        float acc = bm[j];
        #pragma unroll 4
        for (int k = 0; k < 128; ++k)
            acc = fmaf(rr[k], Wm[k * 64 + j], acc);
        out[(size_t)g * 64 + j] = acc;
    }
}

extern "C" void kernel_launch(void* const* d_in, const int* in_sizes, int n_in,
                              void* d_out, int out_size, void* d_ws, size_t ws_size,
                              hipStream_t stream) {
    const float* x    = (const float*)d_in[0];
    const int*  adj   = (const int*)d_in[1];
    const int*  batch = (const int*)d_in[2];
    const float* W1   = (const float*)d_in[3];
    const float* b1   = (const float*)d_in[4];
    const float* W2   = (const float*)d_in[5];
    const float* b2   = (const float*)d_in[6];
    const float* Wm   = (const float*)d_in[7];
    const float* bm   = (const float*)d_in[8];
    float* out = (float*)d_out;

    const int N = in_sizes[0] / 64;
    const int E = in_sizes[1] / 2;
    const int* src = adj;
    const int* dst = adj + E;
    const int B = (N + 255) >> 8;                 // buckets (391)
    const int nblocks = (E + CHUNK - 1) / CHUNK;  // coarse blocks (196)

    // ---- workspace carve (256B aligned) ----
    char* w = (char*)d_ws;
    size_t off = 0;
    auto carve = [&](size_t bytes) -> void* {
        void* p = w + off;
        off += (bytes + 255) & ~(size_t)255;
        return p;
    };
    size_t halfbuf = (size_t)N * 64 * 2;
    size_t cntbytes = (size_t)MAXB * 256 * 4;
    float* dinv    = (float*)carve((size_t)N * 4);
    int*   row_off = (int*)  carve((size_t)(N + 1) * 4);
    int*   esrc    = (int*)  carve((size_t)E * 4);
    unsigned* ebuck= (unsigned*)carve((size_t)E * 4);
    int*   btot    = (int*)  carve((MAXB + 1) * 4);
    int*   bbase   = (int*)  carve((MAXB + 1) * 4);
    int*   goff    = (int*)  carve((NGRAPH + 1) * 4);
    __half* W1s    = (__half*)carve(8192 * 2);
    __half* W2s    = (__half*)carve(8192 * 2);
    __half* xs_h   = (__half*)carve(halfbuf);             // later reused as ts_h
    __half* agg1h  = (__half*)carve(halfbuf > cntbytes ? halfbuf : cntbytes); // cnt pre-agg
    float* h2      = (float*)carve((size_t)N * 64 * 4);
    int*      cnt   = (int*)agg1h;     // dead before agg writes agg1h
    __half* ts_h = xs_h;               // xs_h dead after first agg

    hipMemsetAsync(btot, 0, (MAXB + 1) * 4, stream);

    // weight pre-swizzle + graph segment offsets (independent)
    wconv_kernel<<<1, 256, 0, stream>>>(W1, W2, W1s, W2s);
    goff_kernel<<<(NGRAPH + 256) / 256, 256, 0, stream>>>(batch, N, goff);

    // CSR build (two-level bucket sort) + fused x pre-scale
    coarse_hist_kernel<<<nblocks, 256, 0, stream>>>(dst, E, nblocks, B, cnt, btot);
    offset_scan_kernel<<<B, 256, 0, stream>>>(cnt, btot, bbase, nblocks, B, E);
    coarse_scatter_kernel<<<nblocks, 256, 0, stream>>>(src, dst, E, nblocks, B, cnt, ebuck);
    fine_kernel<<<B, 256, 0, stream>>>(ebuck, bbase, x, N, E, B, row_off, dinv, esrc, xs_h);

    // conv1 aggregate: agg1h = half(dinv*(S+I)xs)
    agg_h2h_kernel<<<(N + 3) / 4, 256, 0, stream>>>(xs_h, esrc, row_off, dinv, agg1h, N);

    // fused MLP: ts_h = half((relu(agg1h@W1 + b1) @ W2) * dinv)
    fusedmlp_kernel<<<(N + 63) / 64, 256, 0, stream>>>(agg1h, W1s, W2s, b1, dinv, ts_h, N);

    // conv2 aggregate: h2 = dinv*(S+I)ts + b2
    agg_h2f_kernel<<<(N + 3) / 4, 256, 0, stream>>>(ts_h, esrc, row_off, dinv, b2, h2, N);

    // fused readout + head
    readout_head_kernel<<<NGRAPH, 256, 0, stream>>>(h2, goff, Wm, bm, out);
}